// Round 2
// baseline (678.357 us; speedup 1.0000x reference)
//
#include <hip/hip_runtime.h>
#include <hip/hip_bf16.h>

typedef __attribute__((ext_vector_type(4))) float f32x4;
typedef __attribute__((ext_vector_type(8))) short bf16x8;
typedef __attribute__((ext_vector_type(4))) short short4v;

#define DEVI __device__ __forceinline__

constexpr int Bc = 2, Tc = 2048, Dc = 2048, Hc = 32, KVc = 8, HDc = 64;
constexpr int GRP = Hc / KVc;           // 4
constexpr float SCALEc = 0.125f;        // 1/sqrt(64)
constexpr float EPSc = 1e-6f;

DEVI short f2b(float f) {
    __hip_bfloat16 h = __float2bfloat16(f);
    short s;
    __builtin_memcpy(&s, &h, sizeof(short));
    return s;
}

// ---------------------------------------------------------------------------
// GEMM: C(MxN,f32) = A(MxK, f32 or bf16) * B(KxN, f32 cast to bf16)
// 128x128 tile, BK=32, 256 threads (4 waves, 2x2 of 64x64), 16x16x32 bf16 MFMA
// ---------------------------------------------------------------------------
template <typename AT>
__global__ __launch_bounds__(256) void gemm128(const AT* __restrict__ A,
                                               const float* __restrict__ Bw,
                                               float* __restrict__ C,
                                               int M, int N, int K) {
    constexpr int BM = 128, BN = 128, BK = 32, LDS_ = BK + 8;  // +8 bf16 pad (16B)
    __shared__ __align__(16) short sA[BM * LDS_];
    __shared__ __align__(16) short sB[BN * LDS_];

    const int tid = threadIdx.x;
    const int wave = tid >> 6, lane = tid & 63;
    const int lhi = lane >> 4, llo = lane & 15;
    const int bm = blockIdx.y * BM, bn = blockIdx.x * BN;
    const int wm = (wave >> 1) * 64, wn = (wave & 1) * 64;

    f32x4 acc[4][4] = {};

    for (int k0 = 0; k0 < K; k0 += BK) {
        // ---- stage A tile (128x32) -> bf16 LDS, row-major
        if constexpr (sizeof(AT) == 4) {
#pragma unroll
            for (int p = 0; p < 4; ++p) {
                int idx = (p * 256 + tid) * 4;
                int r = idx >> 5, c = idx & 31;
                float4 v = *reinterpret_cast<const float4*>(A + (size_t)(bm + r) * K + k0 + c);
                short4v s4 = {f2b(v.x), f2b(v.y), f2b(v.z), f2b(v.w)};
                *reinterpret_cast<short4v*>(&sA[r * LDS_ + c]) = s4;
            }
        } else {
#pragma unroll
            for (int p = 0; p < 2; ++p) {
                int idx = (p * 256 + tid) * 8;
                int r = idx >> 5, c = idx & 31;
                *reinterpret_cast<int4*>(&sA[r * LDS_ + c]) =
                    *reinterpret_cast<const int4*>(A + (size_t)(bm + r) * K + k0 + c);
            }
        }
        // ---- stage B tile (32x128) transposed -> sB[n][k]
        {
            int nn = tid & 127, kg = tid >> 7;  // kg in {0,1}: k-rows [kg*16, kg*16+16)
            alignas(16) short buf[16];
#pragma unroll
            for (int j = 0; j < 16; ++j)
                buf[j] = f2b(Bw[(size_t)(k0 + kg * 16 + j) * N + bn + nn]);
            *reinterpret_cast<int4*>(&sB[nn * LDS_ + kg * 16]) = reinterpret_cast<int4*>(buf)[0];
            *reinterpret_cast<int4*>(&sB[nn * LDS_ + kg * 16 + 8]) = reinterpret_cast<int4*>(buf)[1];
        }
        __syncthreads();

        bf16x8 af[4], bf[4];
#pragma unroll
        for (int i = 0; i < 4; ++i)
            af[i] = *reinterpret_cast<const bf16x8*>(&sA[(wm + i * 16 + llo) * LDS_ + lhi * 8]);
#pragma unroll
        for (int j = 0; j < 4; ++j)
            bf[j] = *reinterpret_cast<const bf16x8*>(&sB[(wn + j * 16 + llo) * LDS_ + lhi * 8]);
#pragma unroll
        for (int i = 0; i < 4; ++i)
#pragma unroll
            for (int j = 0; j < 4; ++j)
                acc[i][j] = __builtin_amdgcn_mfma_f32_16x16x32_bf16(af[i], bf[j], acc[i][j], 0, 0, 0);
        __syncthreads();
    }

#pragma unroll
    for (int i = 0; i < 4; ++i)
#pragma unroll
        for (int j = 0; j < 4; ++j)
#pragma unroll
            for (int r = 0; r < 4; ++r)
                C[(size_t)(bm + wm + i * 16 + lhi * 4 + r) * N + bn + wn + j * 16 + llo] = acc[i][j][r];
}

// ---------------------------------------------------------------------------
// fuse: RMSNorm + RoPE + (optional scale), f32 (B,T,Hx,64) -> bf16 (B,Hx,T,64)
// one 64-lane wave per row
// ---------------------------------------------------------------------------
__global__ __launch_bounds__(256) void fuse_qk(const float* __restrict__ in,
                                               const float* __restrict__ scale,
                                               short* __restrict__ out, int Hx, float mult) {
    int wid = (blockIdx.x * 256 + threadIdx.x) >> 6;
    int d = threadIdx.x & 63;
    int total = Bc * Tc * Hx;
    if (wid >= total) return;
    int h = wid % Hx;
    int bt = wid / Hx;
    int t = bt % Tc;
    int b = bt / Tc;

    float v = in[(size_t)wid * 64 + d];
    float ss = v * v;
#pragma unroll
    for (int m = 1; m < 64; m <<= 1) ss += __shfl_xor(ss, m);
    v = v / sqrtf(ss * (1.0f / 64.0f) + EPSc) * scale[d];

    int i = d & 31;
    float inv_f = exp2f(-0.41524101186092029f * (float)i);  // theta^(-i/32)
    float ang = (float)t * inv_f;
    float sn, cs;
    sincosf(ang, &sn, &cs);
    float other = __shfl_xor(v, 32);
    float o = (d < 32) ? (v * cs - other * sn) : (v * cs + other * sn);
    o *= mult;
    out[((size_t)(b * Hx + h) * Tc + t) * 64 + d] = f2b(o);
}

// V: f32 (B,T,KV,64) -> bf16 (B,KV,T,64)
__global__ __launch_bounds__(256) void fuse_v(const float* __restrict__ in,
                                              short* __restrict__ out) {
    int e4 = blockIdx.x * 256 + threadIdx.x;  // total B*T*KV*16
    if (e4 >= Bc * Tc * KVc * 16) return;
    int d4 = e4 & 15;
    int rid = e4 >> 4;
    int kv = rid % KVc;
    int bt = rid / KVc;
    int t = bt % Tc;
    int b = bt / Tc;
    float4 v = *reinterpret_cast<const float4*>(in + (size_t)rid * 64 + d4 * 4);
    short4v s = {f2b(v.x), f2b(v.y), f2b(v.z), f2b(v.w)};
    *reinterpret_cast<short4v*>(out + ((size_t)(b * KVc + kv) * Tc + t) * 64 + d4 * 4) = s;
}

// ---------------------------------------------------------------------------
// Flash attention, causal GQA.
// grid: (T/64, H, B). 256 threads = 4 waves, each wave 16 q rows.
// Q bf16 (B,H,T,64) pre-scaled; K bf16 (B,KV,T,64); V bf16 (B,KV,T,64)
// out bf16 (B,T,H*64)
// ---------------------------------------------------------------------------
__global__ __launch_bounds__(256) void attn_fwd(const short* __restrict__ Qb,
                                                const short* __restrict__ Kb,
                                                const short* __restrict__ Vb,
                                                short* __restrict__ Ob) {
    constexpr int LK = 72;  // 64 + 8 pad
    __shared__ __align__(16) short sK[64 * LK];
    __shared__ __align__(16) short sVt[64 * LK];
    __shared__ __align__(16) short sP[4][16 * LK];

    const int qt = blockIdx.x, h = blockIdx.y, b = blockIdx.z;
    const int kvh = h / GRP;
    const int tid = threadIdx.x, wave = tid >> 6, lane = tid & 63;
    const int lhi = lane >> 4, llo = lane & 15;

    const short* Qp = Qb + (size_t)(b * Hc + h) * Tc * 64;
    const short* Kp = Kb + (size_t)(b * KVc + kvh) * Tc * 64;
    const short* Vp = Vb + (size_t)(b * KVc + kvh) * Tc * 64;

    const int q0 = qt * 64 + wave * 16;  // this wave's first q row (global)

    bf16x8 qf[2];
    qf[0] = *reinterpret_cast<const bf16x8*>(Qp + (size_t)(q0 + llo) * 64 + lhi * 8);
    qf[1] = *reinterpret_cast<const bf16x8*>(Qp + (size_t)(q0 + llo) * 64 + 32 + lhi * 8);

    f32x4 o[4] = {};
    float mrow[4], lrow[4];
#pragma unroll
    for (int r = 0; r < 4; ++r) { mrow[r] = -1e30f; lrow[r] = 0.f; }

    for (int kt = 0; kt <= qt; ++kt) {
        // stage K tile [64][64]
#pragma unroll
        for (int p = 0; p < 2; ++p) {
            int idx = p * 256 + tid;
            int rr = idx >> 3, cc = (idx & 7) * 8;
            *reinterpret_cast<int4*>(&sK[rr * LK + cc]) =
                *reinterpret_cast<const int4*>(Kp + (size_t)(kt * 64 + rr) * 64 + cc);
        }
        // stage V transposed: sVt[d][kv]
#pragma unroll
        for (int p = 0; p < 2; ++p) {
            int idx = p * 256 + tid;
            int rr = idx >> 3, cc = (idx & 7) * 8;
            int4 raw = *reinterpret_cast<const int4*>(Vp + (size_t)(kt * 64 + rr) * 64 + cc);
            const short* rs = reinterpret_cast<const short*>(&raw);
#pragma unroll
            for (int j = 0; j < 8; ++j) sVt[(cc + j) * LK + rr] = rs[j];
        }
        __syncthreads();

        // S = Q K^T  (per wave: 16 x 64)
        f32x4 st[4];
#pragma unroll
        for (int n = 0; n < 4; ++n) {
            f32x4 z = {0.f, 0.f, 0.f, 0.f};
            bf16x8 kf0 = *reinterpret_cast<const bf16x8*>(&sK[(n * 16 + llo) * LK + lhi * 8]);
            bf16x8 kf1 = *reinterpret_cast<const bf16x8*>(&sK[(n * 16 + llo) * LK + 32 + lhi * 8]);
            z = __builtin_amdgcn_mfma_f32_16x16x32_bf16(qf[0], kf0, z, 0, 0, 0);
            z = __builtin_amdgcn_mfma_f32_16x16x32_bf16(qf[1], kf1, z, 0, 0, 0);
            st[n] = z;
        }
        if (kt == qt) {  // diagonal tile: causal mask
#pragma unroll
            for (int n = 0; n < 4; ++n)
#pragma unroll
                for (int r = 0; r < 4; ++r) {
                    int kvcol = kt * 64 + n * 16 + llo;
                    int qrow = q0 + lhi * 4 + r;
                    if (kvcol > qrow) st[n][r] = -1e30f;
                }
        }
        // online softmax (rows live in lanes sharing lhi; reduce over llo)
        float rmax[4];
#pragma unroll
        for (int r = 0; r < 4; ++r)
            rmax[r] = fmaxf(fmaxf(st[0][r], st[1][r]), fmaxf(st[2][r], st[3][r]));
#pragma unroll
        for (int m = 1; m < 16; m <<= 1)
#pragma unroll
            for (int r = 0; r < 4; ++r) rmax[r] = fmaxf(rmax[r], __shfl_xor(rmax[r], m));
        float alpha[4];
#pragma unroll
        for (int r = 0; r < 4; ++r) {
            float mn = fmaxf(mrow[r], rmax[r]);
            alpha[r] = expf(mrow[r] - mn);
            mrow[r] = mn;
        }
        float rsum[4] = {0.f, 0.f, 0.f, 0.f};
#pragma unroll
        for (int n = 0; n < 4; ++n)
#pragma unroll
            for (int r = 0; r < 4; ++r) {
                float pv = expf(st[n][r] - mrow[r]);
                st[n][r] = pv;
                rsum[r] += pv;
            }
#pragma unroll
        for (int m = 1; m < 16; m <<= 1)
#pragma unroll
            for (int r = 0; r < 4; ++r) rsum[r] += __shfl_xor(rsum[r], m);
#pragma unroll
        for (int r = 0; r < 4; ++r) lrow[r] = lrow[r] * alpha[r] + rsum[r];
#pragma unroll
        for (int j = 0; j < 4; ++j)
#pragma unroll
            for (int r = 0; r < 4; ++r) o[j][r] *= alpha[r];

        // write P (16x64 per wave) to wave-private LDS
        short* Pw = &sP[wave][0];
#pragma unroll
        for (int n = 0; n < 4; ++n)
#pragma unroll
            for (int r = 0; r < 4; ++r)
                Pw[(lhi * 4 + r) * LK + n * 16 + llo] = f2b(st[n][r]);

        // O += P @ V
#pragma unroll
        for (int kk = 0; kk < 2; ++kk) {
            bf16x8 pf = *reinterpret_cast<const bf16x8*>(&Pw[llo * LK + kk * 32 + lhi * 8]);
#pragma unroll
            for (int j = 0; j < 4; ++j) {
                bf16x8 vf = *reinterpret_cast<const bf16x8*>(&sVt[(j * 16 + llo) * LK + kk * 32 + lhi * 8]);
                o[j] = __builtin_amdgcn_mfma_f32_16x16x32_bf16(pf, vf, o[j], 0, 0, 0);
            }
        }
        __syncthreads();
    }

    // epilogue: normalize and store bf16 to (B,T,H*64)
#pragma unroll
    for (int r = 0; r < 4; ++r) {
        int q = q0 + lhi * 4 + r;
        float inv = 1.0f / lrow[r];
#pragma unroll
        for (int j = 0; j < 4; ++j)
            Ob[((size_t)(b * Tc + q) * Hc + h) * 64 + j * 16 + llo] = f2b(o[j][r] * inv);
    }
}

// ---------------------------------------------------------------------------
extern "C" void kernel_launch(void* const* d_in, const int* in_sizes, int n_in,
                              void* d_out, int out_size, void* d_ws, size_t ws_size,
                              hipStream_t stream) {
    const float* x  = (const float*)d_in[0];
    const float* Wq = (const float*)d_in[1];
    const float* Wk = (const float*)d_in[2];
    const float* Wv = (const float*)d_in[3];
    const float* Wo = (const float*)d_in[4];
    const float* qs = (const float*)d_in[5];
    const float* ks = (const float*)d_in[6];
    float* out = (float*)d_out;

    char* w = (char*)d_ws;
    float* qf = (float*)(w);                    // 4096*2048*4 = 33554432
    float* kf = (float*)(w + 33554432);         // 4096*512*4  =  8388608
    float* vf = (float*)(w + 41943040);         // 4096*512*4  =  8388608
    short* qb = (short*)(w + 50331648);         // 4096*2048*2 = 16777216
    short* kb = (short*)(w + 67108864);         // 4096*512*2  =  4194304
    short* vb = (short*)(w + 71303168);         // 4096*512*2  =  4194304
    short* ob = (short*)(w);                    // reuse qf region (qf dead by then)

    dim3 blk(256);
    // QKV projections (f32 in, bf16 MFMA, f32 out)
    gemm128<float><<<dim3(16, 32), blk, 0, stream>>>(x, Wq, qf, 4096, 2048, 2048);
    gemm128<float><<<dim3(4, 32), blk, 0, stream>>>(x, Wk, kf, 4096, 512, 2048);
    gemm128<float><<<dim3(4, 32), blk, 0, stream>>>(x, Wv, vf, 4096, 512, 2048);
    // RMSNorm + RoPE + relayout (SCALE folded into Q)
    fuse_qk<<<dim3((Bc * Tc * Hc) / 4), blk, 0, stream>>>(qf, qs, qb, Hc, SCALEc);
    fuse_qk<<<dim3((Bc * Tc * KVc) / 4), blk, 0, stream>>>(kf, ks, kb, KVc, 1.0f);
    fuse_v<<<dim3((Bc * Tc * KVc * 16) / 256), blk, 0, stream>>>(vf, vb);
    // flash attention
    attn_fwd<<<dim3(Tc / 64, Hc, Bc), blk, 0, stream>>>(qb, kb, vb, ob);
    // output projection
    gemm128<short><<<dim3(16, 32), blk, 0, stream>>>(ob, Wo, out, 4096, 2048, 2048);
}

// Round 3
// 374.490 us; speedup vs baseline: 1.8114x; 1.8114x over previous
//
#include <hip/hip_runtime.h>
#include <hip/hip_bf16.h>

typedef __attribute__((ext_vector_type(4))) float f32x4;
typedef __attribute__((ext_vector_type(8))) short bf16x8;
typedef __attribute__((ext_vector_type(4))) short short4v;

#define DEVI __device__ __forceinline__

constexpr int Bc = 2, Tc = 2048, Dc = 2048, Hc = 32, KVc = 8, HDc = 64;
constexpr int GRP = Hc / KVc;  // 4
constexpr float EPSc = 1e-6f;
// SCALE * log2(e) folded into Q so softmax uses exp2
constexpr float QMULT = 0.125f * 1.4426950408889634f;

DEVI short f2b(float f) {
    __hip_bfloat16 h = __float2bfloat16(f);
    short s;
    __builtin_memcpy(&s, &h, sizeof(short));
    return s;
}
DEVI float b2f(short s) {
    unsigned int u = ((unsigned int)(unsigned short)s) << 16;
    float f;
    __builtin_memcpy(&f, &u, sizeof(float));
    return f;
}

#define GLOAD16(g, l)                                                        \
    __builtin_amdgcn_global_load_lds(                                        \
        (const __attribute__((address_space(1))) void*)(g),                  \
        (__attribute__((address_space(3))) void*)(l), 16, 0, 0)

// ---------------------------------------------------------------------------
// prep: f32 -> bf16 convert (x), each thread 8 elems
// ---------------------------------------------------------------------------
__global__ __launch_bounds__(256) void convert_x(const float* __restrict__ in,
                                                 short* __restrict__ out) {
    size_t i = ((size_t)blockIdx.x * 256 + threadIdx.x) * 8;
    float4 a = *reinterpret_cast<const float4*>(in + i);
    float4 b = *reinterpret_cast<const float4*>(in + i + 4);
    bf16x8 o = {f2b(a.x), f2b(a.y), f2b(a.z), f2b(a.w),
                f2b(b.x), f2b(b.y), f2b(b.z), f2b(b.w)};
    *reinterpret_cast<bf16x8*>(out + i) = o;
}

// ---------------------------------------------------------------------------
// prep: transpose weight f32 (R x C) -> bf16 (C x R).  grid (C/64, R/64)
// ---------------------------------------------------------------------------
__global__ __launch_bounds__(256) void tr_w(const float* __restrict__ in,
                                            short* __restrict__ out, int R, int C) {
    __shared__ __align__(16) short t[64][72];
    const int n0 = blockIdx.x * 64, k0 = blockIdx.y * 64;
    const int rl = threadIdx.x >> 2, q = threadIdx.x & 3;
#pragma unroll
    for (int jj = 0; jj < 4; ++jj) {
        float4 v = *reinterpret_cast<const float4*>(in + (size_t)(k0 + rl) * C + n0 + q * 16 + jj * 4);
        short4v s = {f2b(v.x), f2b(v.y), f2b(v.z), f2b(v.w)};
        *reinterpret_cast<short4v*>(&t[rl][q * 16 + jj * 4]) = s;
    }
    __syncthreads();
    alignas(16) short buf[16];
#pragma unroll
    for (int e = 0; e < 16; ++e) buf[e] = t[q * 16 + e][rl];
    short* dst = out + (size_t)(n0 + rl) * R + k0 + q * 16;
    *reinterpret_cast<int4*>(dst) = reinterpret_cast<int4*>(buf)[0];
    *reinterpret_cast<int4*>(dst + 8) = reinterpret_cast<int4*>(buf)[1];
}

// ---------------------------------------------------------------------------
// GEMM (m97 structure): C(MxN) = A(MxK,bf16 rowmajor) * Bt(NxK,bf16 rowmajor)^T
// 128x128 tile, BK=32, 256 thr (4 waves 2x2), global_load_lds w16 staging
// ---------------------------------------------------------------------------
template <typename CT>
__global__ __launch_bounds__(256) void gemm_bt(const short* __restrict__ A,
                                               const short* __restrict__ Bt,
                                               CT* __restrict__ C, int M, int N, int K) {
    __shared__ __align__(16) short sA[128 * 32];
    __shared__ __align__(16) short sB[128 * 32];

    const int tid = threadIdx.x;
    const int wave = tid >> 6, lane = tid & 63;
    const int lhi = lane >> 4, llo = lane & 15;
    const int bm = blockIdx.y * 128, bn = blockIdx.x * 128;
    const int wm = (wave >> 1) * 64, wn = (wave & 1) * 64;

    f32x4 acc[4][4] = {};

    for (int k0 = 0; k0 < K; k0 += 32) {
#pragma unroll
        for (int i = 0; i < 2; ++i) {
            int c = i * 256 + tid;
            int r = c >> 2, ch = (c & 3) * 8;
            GLOAD16(A + (size_t)(bm + r) * K + k0 + ch, &sA[c * 8]);
            GLOAD16(Bt + (size_t)(bn + r) * K + k0 + ch, &sB[c * 8]);
        }
        __syncthreads();

        bf16x8 af[4], bf[4];
#pragma unroll
        for (int i = 0; i < 4; ++i)
            af[i] = *reinterpret_cast<const bf16x8*>(&sA[(wm + i * 16 + llo) * 32 + lhi * 8]);
#pragma unroll
        for (int j = 0; j < 4; ++j)
            bf[j] = *reinterpret_cast<const bf16x8*>(&sB[(wn + j * 16 + llo) * 32 + lhi * 8]);
#pragma unroll
        for (int i = 0; i < 4; ++i)
#pragma unroll
            for (int j = 0; j < 4; ++j)
                acc[i][j] = __builtin_amdgcn_mfma_f32_16x16x32_bf16(af[i], bf[j], acc[i][j], 0, 0, 0);
        __syncthreads();
    }

#pragma unroll
    for (int i = 0; i < 4; ++i)
#pragma unroll
        for (int j = 0; j < 4; ++j)
#pragma unroll
            for (int r = 0; r < 4; ++r) {
                size_t idx = (size_t)(bm + wm + i * 16 + lhi * 4 + r) * N + bn + wn + j * 16 + llo;
                if constexpr (sizeof(CT) == 2)
                    C[idx] = f2b(acc[i][j][r]);
                else
                    C[idx] = acc[i][j][r];
            }
}

// ---------------------------------------------------------------------------
// fuse: RMSNorm + RoPE + scale, bf16 (B*T rows, ldin cols) -> bf16 (B,Hx,T,64)
// one 64-lane wave per row
// ---------------------------------------------------------------------------
__global__ __launch_bounds__(256) void fuse_qk(const short* __restrict__ in,
                                               const float* __restrict__ scale,
                                               short* __restrict__ out, int Hx, int ldin,
                                               float mult) {
    int wid = (blockIdx.x * 256 + threadIdx.x) >> 6;
    int d = threadIdx.x & 63;
    if (wid >= Bc * Tc * Hx) return;
    int h = wid % Hx;
    int bt = wid / Hx;
    int t = bt % Tc;
    int b = bt / Tc;

    float v = b2f(in[(size_t)bt * ldin + h * 64 + d]);
    float ss = v * v;
#pragma unroll
    for (int m = 1; m < 64; m <<= 1) ss += __shfl_xor(ss, m);
    v = v / sqrtf(ss * (1.0f / 64.0f) + EPSc) * scale[d];

    int i = d & 31;
    float inv_f = exp2f(-0.41524101186092029f * (float)i);  // theta^(-i/32)
    float ang = (float)t * inv_f;
    float sn, cs;
    sincosf(ang, &sn, &cs);
    float other = __shfl_xor(v, 32);
    float o = (d < 32) ? (v * cs - other * sn) : (v * cs + other * sn);
    o *= mult;
    out[((size_t)(b * Hx + h) * Tc + t) * 64 + d] = f2b(o);
}

// ---------------------------------------------------------------------------
// fuse: V part of kvf -> transposed tiles  vt[b][kv][tile][d(64)][t_local(64)]
// grid (32 tiles, 8 kv, 2 b)
// ---------------------------------------------------------------------------
__global__ __launch_bounds__(256) void fuse_vt(const short* __restrict__ kvf,
                                               short* __restrict__ vt) {
    __shared__ __align__(16) short t[64][72];
    const int tile = blockIdx.x, kv = blockIdx.y, b = blockIdx.z;
    const int tl = threadIdx.x >> 2, q = threadIdx.x & 3;
    const short* src = kvf + (size_t)(b * 2048 + tile * 64 + tl) * 1024 + 512 + kv * 64 + q * 16;
    *reinterpret_cast<bf16x8*>(&t[tl][q * 16]) = *reinterpret_cast<const bf16x8*>(src);
    *reinterpret_cast<bf16x8*>(&t[tl][q * 16 + 8]) = *reinterpret_cast<const bf16x8*>(src + 8);
    __syncthreads();
    alignas(16) short buf[16];
#pragma unroll
    for (int e = 0; e < 16; ++e) buf[e] = t[q * 16 + e][tl];
    short* dst = vt + ((size_t)(b * 8 + kv) * 32 + tile) * 4096 + tl * 64 + q * 16;
    *reinterpret_cast<int4*>(dst) = reinterpret_cast<int4*>(buf)[0];
    *reinterpret_cast<int4*>(dst + 8) = reinterpret_cast<int4*>(buf)[1];
}

// ---------------------------------------------------------------------------
// Flash attention, causal GQA, swapped-QK^T form.
// grid (16 qtiles of 128, 32 h, 2 b); 256 thr = 4 waves, 32 q rows per wave.
// Q bf16 (B,H,T,64) pre-scaled by QMULT; K bf16 (B,KV,T,64);
// Vt tiles (B,KV,32,64d,64kv); out bf16 (B,T,H*64)
// ---------------------------------------------------------------------------
__global__ __launch_bounds__(256) void attn_fwd(const short* __restrict__ Qb,
                                                const short* __restrict__ Kb,
                                                const short* __restrict__ Vt,
                                                short* __restrict__ Ob) {
    __shared__ __align__(16) short sK[64 * 64];
    __shared__ __align__(16) short sV[64 * 64];
    __shared__ __align__(16) short sP[4][32 * 72];

    const int qt = 15 - (int)blockIdx.x;  // longest blocks first
    const int h = blockIdx.y, b = blockIdx.z;
    const int kvh = h >> 2;
    const int tid = threadIdx.x, wave = tid >> 6, lane = tid & 63;
    const int lhi = lane >> 4, llo = lane & 15;

    const short* Qp = Qb + (size_t)(b * Hc + h) * Tc * 64;
    const short* Kp = Kb + (size_t)(b * KVc + kvh) * Tc * 64;
    const short* Vp = Vt + (size_t)(b * KVc + kvh) * 32 * 4096;

    const int Q0 = qt * 128 + wave * 32;
    const int ktmax_w = (Q0 + 31) >> 6;
    const int ktmax_b = 2 * qt + 1;

    bf16x8 qf[2][2];
#pragma unroll
    for (int q16 = 0; q16 < 2; ++q16)
#pragma unroll
        for (int kk = 0; kk < 2; ++kk)
            qf[q16][kk] = *reinterpret_cast<const bf16x8*>(
                Qp + (size_t)(Q0 + q16 * 16 + llo) * 64 + kk * 32 + lhi * 8);

    f32x4 o[2][4] = {};
    float mreg[2] = {-1e30f, -1e30f};
    float lreg[2] = {0.f, 0.f};

    for (int kt = 0; kt <= ktmax_b; ++kt) {
        // stage K tile and V^T tile (swizzled source -> linear LDS dest)
#pragma unroll
        for (int i = 0; i < 2; ++i) {
            int c = i * 256 + tid;
            int row = c >> 3, slot = c & 7;
            int ss = slot ^ (row & 7);
            GLOAD16(Kp + (size_t)(kt * 64 + row) * 64 + ss * 8, &sK[c * 8]);
            GLOAD16(Vp + (size_t)kt * 4096 + row * 64 + ss * 8, &sV[c * 8]);
        }
        __syncthreads();

        if (kt <= ktmax_w) {
            // S^T = K Q^T : C[kv_local=lhi*4+r][q_local=llo] per (n, q16)
            f32x4 st[2][4];
#pragma unroll
            for (int n = 0; n < 4; ++n) {
                int krow = n * 16 + llo;
                bf16x8 ka0 = *reinterpret_cast<const bf16x8*>(
                    &sK[krow * 64 + ((lhi ^ (krow & 7)) << 3)]);
                bf16x8 ka1 = *reinterpret_cast<const bf16x8*>(
                    &sK[krow * 64 + (((4 + lhi) ^ (krow & 7)) << 3)]);
                f32x4 z = {0.f, 0.f, 0.f, 0.f};
                st[0][n] = __builtin_amdgcn_mfma_f32_16x16x32_bf16(ka0, qf[0][0], z, 0, 0, 0);
                st[0][n] = __builtin_amdgcn_mfma_f32_16x16x32_bf16(ka1, qf[0][1], st[0][n], 0, 0, 0);
                st[1][n] = __builtin_amdgcn_mfma_f32_16x16x32_bf16(ka0, qf[1][0], z, 0, 0, 0);
                st[1][n] = __builtin_amdgcn_mfma_f32_16x16x32_bf16(ka1, qf[1][1], st[1][n], 0, 0, 0);
            }
            if (kt == ktmax_w) {  // causal mask (diagonal region only)
#pragma unroll
                for (int q16 = 0; q16 < 2; ++q16) {
                    int qg = Q0 + q16 * 16 + llo;
#pragma unroll
                    for (int n = 0; n < 4; ++n)
#pragma unroll
                        for (int r = 0; r < 4; ++r) {
                            int kvg = kt * 64 + n * 16 + lhi * 4 + r;
                            if (kvg > qg) st[q16][n][r] = -1e30f;
                        }
                }
            }
            // online softmax; each lane owns row q = Q0 + q16*16 + llo
            float alpha[2];
#pragma unroll
            for (int q16 = 0; q16 < 2; ++q16) {
                float pm = st[q16][0][0];
#pragma unroll
                for (int n = 0; n < 4; ++n)
#pragma unroll
                    for (int r = 0; r < 4; ++r) pm = fmaxf(pm, st[q16][n][r]);
                pm = fmaxf(pm, __shfl_xor(pm, 16));
                pm = fmaxf(pm, __shfl_xor(pm, 32));
                float mn = fmaxf(mreg[q16], pm);
                alpha[q16] = __builtin_amdgcn_exp2f(mreg[q16] - mn);
                mreg[q16] = mn;
                float ps = 0.f;
#pragma unroll
                for (int n = 0; n < 4; ++n)
#pragma unroll
                    for (int r = 0; r < 4; ++r) {
                        float p = __builtin_amdgcn_exp2f(st[q16][n][r] - mn);
                        st[q16][n][r] = p;
                        ps += p;
                    }
                ps += __shfl_xor(ps, 16);
                ps += __shfl_xor(ps, 32);
                lreg[q16] = lreg[q16] * alpha[q16] + ps;
            }
            // rescale O (alpha lives at lane llo==row; broadcast to C rows)
#pragma unroll
            for (int q16 = 0; q16 < 2; ++q16)
#pragma unroll
                for (int r = 0; r < 4; ++r) {
                    float ar = __shfl(alpha[q16], lhi * 4 + r);
#pragma unroll
                    for (int j = 0; j < 4; ++j) o[q16][j][r] *= ar;
                }
            // store P rows to wave-private LDS (b64 stores)
#pragma unroll
            for (int q16 = 0; q16 < 2; ++q16)
#pragma unroll
                for (int n = 0; n < 4; ++n) {
                    short4v p4 = {f2b(st[q16][n][0]), f2b(st[q16][n][1]),
                                  f2b(st[q16][n][2]), f2b(st[q16][n][3])};
                    *reinterpret_cast<short4v*>(
                        &sP[wave][(q16 * 16 + llo) * 72 + n * 16 + lhi * 4]) = p4;
                }
            // O += P V
#pragma unroll
            for (int kk = 0; kk < 2; ++kk) {
                bf16x8 pa0 = *reinterpret_cast<const bf16x8*>(
                    &sP[wave][(0 * 16 + llo) * 72 + kk * 32 + lhi * 8]);
                bf16x8 pa1 = *reinterpret_cast<const bf16x8*>(
                    &sP[wave][(1 * 16 + llo) * 72 + kk * 32 + lhi * 8]);
#pragma unroll
                for (int j = 0; j < 4; ++j) {
                    int vrow = j * 16 + llo;
                    bf16x8 vf = *reinterpret_cast<const bf16x8*>(
                        &sV[vrow * 64 + ((((kk * 4) + lhi) ^ (vrow & 7)) << 3)]);
                    o[0][j] = __builtin_amdgcn_mfma_f32_16x16x32_bf16(pa0, vf, o[0][j], 0, 0, 0);
                    o[1][j] = __builtin_amdgcn_mfma_f32_16x16x32_bf16(pa1, vf, o[1][j], 0, 0, 0);
                }
            }
        }
        __syncthreads();
    }

    // epilogue: normalize, store bf16 (B,T,H*64)
#pragma unroll
    for (int q16 = 0; q16 < 2; ++q16) {
        float inv = 1.0f / lreg[q16];
#pragma unroll
        for (int r = 0; r < 4; ++r) {
            float ivr = __shfl(inv, lhi * 4 + r);
            int qrow = Q0 + q16 * 16 + lhi * 4 + r;
#pragma unroll
            for (int j = 0; j < 4; ++j)
                Ob[((size_t)(b * Tc + qrow)) * 2048 + h * 64 + j * 16 + llo] =
                    f2b(o[q16][j][r] * ivr);
        }
    }
}

// ---------------------------------------------------------------------------
extern "C" void kernel_launch(void* const* d_in, const int* in_sizes, int n_in,
                              void* d_out, int out_size, void* d_ws, size_t ws_size,
                              hipStream_t stream) {
    const float* x  = (const float*)d_in[0];
    const float* Wq = (const float*)d_in[1];
    const float* Wk = (const float*)d_in[2];
    const float* Wv = (const float*)d_in[3];
    const float* Wo = (const float*)d_in[4];
    const float* qs = (const float*)d_in[5];
    const float* ks = (const float*)d_in[6];
    float* out = (float*)d_out;

    char* w = (char*)d_ws;
    short* xb   = (short*)(w);                  // 16,777,216  (later: ob)
    short* WqT  = (short*)(w + 16777216);       //  8,388,608  (later: vt)
    short* WkvT = (short*)(w + 25165824);       //  4,194,304
    short* WoT  = (short*)(w + 29360128);       //  8,388,608
    short* qfb  = (short*)(w + 37748736);       // 16,777,216
    short* kvf  = (short*)(w + 54525952);       //  8,388,608
    short* qb   = (short*)(w + 62914560);       // 16,777,216
    short* kb   = (short*)(w + 79691776);       //  4,194,304
    short* vt   = WqT;                          // alias (WqT dead after Q gemm)
    short* ob   = xb;                           // alias (xb dead after gemms)

    dim3 blk(256);
    // prep: bf16 convert + weight transposes
    convert_x<<<dim3(4096), blk, 0, stream>>>(x, xb);
    tr_w<<<dim3(32, 32), blk, 0, stream>>>(Wq, WqT, 2048, 2048);
    tr_w<<<dim3(8, 32), blk, 0, stream>>>(Wk, WkvT, 2048, 512);
    tr_w<<<dim3(8, 32), blk, 0, stream>>>(Wv, WkvT + (size_t)512 * 2048, 2048, 512);
    tr_w<<<dim3(32, 32), blk, 0, stream>>>(Wo, WoT, 2048, 2048);
    // projections (bf16 out)
    gemm_bt<short><<<dim3(16, 32), blk, 0, stream>>>(xb, WqT, qfb, 4096, 2048, 2048);
    gemm_bt<short><<<dim3(8, 32), blk, 0, stream>>>(xb, WkvT, kvf, 4096, 1024, 2048);
    // RMSNorm + RoPE (+SCALE*log2e on Q) + relayout
    fuse_qk<<<dim3(32768), blk, 0, stream>>>(qfb, qs, qb, Hc, 2048, QMULT);
    fuse_qk<<<dim3(8192), blk, 0, stream>>>(kvf, ks, kb, KVc, 1024, 1.0f);
    fuse_vt<<<dim3(32, 8, 2), blk, 0, stream>>>(kvf, vt);
    // flash attention
    attn_fwd<<<dim3(16, 32, 2), blk, 0, stream>>>(qb, kb, vt, ob);
    // output projection (f32 out)
    gemm_bt<float><<<dim3(16, 32), blk, 0, stream>>>(ob, WoT, out, 4096, 2048, 2048);
}

// Round 4
// 312.039 us; speedup vs baseline: 2.1740x; 1.2001x over previous
//
#include <hip/hip_runtime.h>
#include <hip/hip_bf16.h>

typedef __attribute__((ext_vector_type(4))) float f32x4;
typedef __attribute__((ext_vector_type(8))) short bf16x8;
typedef __attribute__((ext_vector_type(4))) short short4v;

#define DEVI __device__ __forceinline__

constexpr int Bc = 2, Tc = 2048, Dc = 2048, Hc = 32, KVc = 8, HDc = 64;
constexpr int GRP = Hc / KVc;  // 4
constexpr float EPSc = 1e-6f;
// SCALE * log2(e) folded into Q so softmax uses exp2
constexpr float QMULT = 0.125f * 1.4426950408889634f;

DEVI short f2b(float f) {
    __hip_bfloat16 h = __float2bfloat16(f);
    short s;
    __builtin_memcpy(&s, &h, sizeof(short));
    return s;
}
DEVI float b2f(short s) {
    unsigned int u = ((unsigned int)(unsigned short)s) << 16;
    float f;
    __builtin_memcpy(&f, &u, sizeof(float));
    return f;
}

#define GLOAD16(g, l)                                                        \
    __builtin_amdgcn_global_load_lds(                                        \
        (const __attribute__((address_space(1))) void*)(g),                  \
        (__attribute__((address_space(3))) void*)(l), 16, 0, 0)

// ---------------------------------------------------------------------------
// prep: f32 -> bf16 convert (x), each thread 8 elems
// ---------------------------------------------------------------------------
__global__ __launch_bounds__(256) void convert_x(const float* __restrict__ in,
                                                 short* __restrict__ out) {
    size_t i = ((size_t)blockIdx.x * 256 + threadIdx.x) * 8;
    float4 a = *reinterpret_cast<const float4*>(in + i);
    float4 b = *reinterpret_cast<const float4*>(in + i + 4);
    bf16x8 o = {f2b(a.x), f2b(a.y), f2b(a.z), f2b(a.w),
                f2b(b.x), f2b(b.y), f2b(b.z), f2b(b.w)};
    *reinterpret_cast<bf16x8*>(out + i) = o;
}

// ---------------------------------------------------------------------------
// prep: transpose weight f32 (R x C) -> bf16 (C x R).  grid (C/64, R/64)
// ---------------------------------------------------------------------------
__global__ __launch_bounds__(256) void tr_w(const float* __restrict__ in,
                                            short* __restrict__ out, int R, int C) {
    __shared__ __align__(16) short t[64][72];
    const int n0 = blockIdx.x * 64, k0 = blockIdx.y * 64;
    const int rl = threadIdx.x >> 2, q = threadIdx.x & 3;
#pragma unroll
    for (int jj = 0; jj < 4; ++jj) {
        float4 v = *reinterpret_cast<const float4*>(in + (size_t)(k0 + rl) * C + n0 + q * 16 + jj * 4);
        short4v s = {f2b(v.x), f2b(v.y), f2b(v.z), f2b(v.w)};
        *reinterpret_cast<short4v*>(&t[rl][q * 16 + jj * 4]) = s;
    }
    __syncthreads();
    alignas(16) short buf[16];
#pragma unroll
    for (int e = 0; e < 16; ++e) buf[e] = t[q * 16 + e][rl];
    short* dst = out + (size_t)(n0 + rl) * R + k0 + q * 16;
    *reinterpret_cast<int4*>(dst) = reinterpret_cast<int4*>(buf)[0];
    *reinterpret_cast<int4*>(dst + 8) = reinterpret_cast<int4*>(buf)[1];
}

// ---------------------------------------------------------------------------
// GEMM (m97 structure): C(MxN) = A(MxK,bf16 rowmajor) * Bt(NxK,bf16 rowmajor)^T
// 128x128 tile, BK=32, 256 thr (4 waves 2x2), global_load_lds w16 staging
// ---------------------------------------------------------------------------
template <typename CT>
__global__ __launch_bounds__(256) void gemm_bt(const short* __restrict__ A,
                                               const short* __restrict__ Bt,
                                               CT* __restrict__ C, int M, int N, int K) {
    __shared__ __align__(16) short sA[128 * 32];
    __shared__ __align__(16) short sB[128 * 32];

    const int tid = threadIdx.x;
    const int wave = tid >> 6, lane = tid & 63;
    const int lhi = lane >> 4, llo = lane & 15;
    const int bm = blockIdx.y * 128, bn = blockIdx.x * 128;
    const int wm = (wave >> 1) * 64, wn = (wave & 1) * 64;

    f32x4 acc[4][4] = {};

    for (int k0 = 0; k0 < K; k0 += 32) {
#pragma unroll
        for (int i = 0; i < 2; ++i) {
            int c = i * 256 + tid;
            int r = c >> 2, ch = (c & 3) * 8;
            GLOAD16(A + (size_t)(bm + r) * K + k0 + ch, &sA[c * 8]);
            GLOAD16(Bt + (size_t)(bn + r) * K + k0 + ch, &sB[c * 8]);
        }
        __syncthreads();

        bf16x8 af[4], bf[4];
#pragma unroll
        for (int i = 0; i < 4; ++i)
            af[i] = *reinterpret_cast<const bf16x8*>(&sA[(wm + i * 16 + llo) * 32 + lhi * 8]);
#pragma unroll
        for (int j = 0; j < 4; ++j)
            bf[j] = *reinterpret_cast<const bf16x8*>(&sB[(wn + j * 16 + llo) * 32 + lhi * 8]);
#pragma unroll
        for (int i = 0; i < 4; ++i)
#pragma unroll
            for (int j = 0; j < 4; ++j)
                acc[i][j] = __builtin_amdgcn_mfma_f32_16x16x32_bf16(af[i], bf[j], acc[i][j], 0, 0, 0);
        __syncthreads();
    }

#pragma unroll
    for (int i = 0; i < 4; ++i)
#pragma unroll
        for (int j = 0; j < 4; ++j)
#pragma unroll
            for (int r = 0; r < 4; ++r) {
                size_t idx = (size_t)(bm + wm + i * 16 + lhi * 4 + r) * N + bn + wn + j * 16 + llo;
                if constexpr (sizeof(CT) == 2)
                    C[idx] = f2b(acc[i][j][r]);
                else
                    C[idx] = acc[i][j][r];
            }
}

// ---------------------------------------------------------------------------
// fuse: RMSNorm + RoPE + scale, bf16 (B*T rows, ldin cols) -> bf16 (B,Hx,T,64)
// one 64-lane wave per row
// ---------------------------------------------------------------------------
__global__ __launch_bounds__(256) void fuse_qk(const short* __restrict__ in,
                                               const float* __restrict__ scale,
                                               short* __restrict__ out, int Hx, int ldin,
                                               float mult) {
    int wid = (blockIdx.x * 256 + threadIdx.x) >> 6;
    int d = threadIdx.x & 63;
    if (wid >= Bc * Tc * Hx) return;
    int h = wid % Hx;
    int bt = wid / Hx;
    int t = bt % Tc;
    int b = bt / Tc;

    float v = b2f(in[(size_t)bt * ldin + h * 64 + d]);
    float ss = v * v;
#pragma unroll
    for (int m = 1; m < 64; m <<= 1) ss += __shfl_xor(ss, m);
    v = v / sqrtf(ss * (1.0f / 64.0f) + EPSc) * scale[d];

    int i = d & 31;
    float inv_f = exp2f(-0.41524101186092029f * (float)i);  // theta^(-i/32)
    float ang = (float)t * inv_f;
    float sn, cs;
    sincosf(ang, &sn, &cs);
    float other = __shfl_xor(v, 32);
    float o = (d < 32) ? (v * cs - other * sn) : (v * cs + other * sn);
    o *= mult;
    out[((size_t)(b * Hx + h) * Tc + t) * 64 + d] = f2b(o);
}

// ---------------------------------------------------------------------------
// fuse: V part of kvf -> transposed tiles  vt[b][kv][tile][d(64)][t_local(64)]
// grid (32 tiles, 8 kv, 2 b)
// ---------------------------------------------------------------------------
__global__ __launch_bounds__(256) void fuse_vt(const short* __restrict__ kvf,
                                               short* __restrict__ vt) {
    __shared__ __align__(16) short t[64][72];
    const int tile = blockIdx.x, kv = blockIdx.y, b = blockIdx.z;
    const int tl = threadIdx.x >> 2, q = threadIdx.x & 3;
    const short* src = kvf + (size_t)(b * 2048 + tile * 64 + tl) * 1024 + 512 + kv * 64 + q * 16;
    *reinterpret_cast<bf16x8*>(&t[tl][q * 16]) = *reinterpret_cast<const bf16x8*>(src);
    *reinterpret_cast<bf16x8*>(&t[tl][q * 16 + 8]) = *reinterpret_cast<const bf16x8*>(src + 8);
    __syncthreads();
    alignas(16) short buf[16];
#pragma unroll
    for (int e = 0; e < 16; ++e) buf[e] = t[q * 16 + e][tl];
    short* dst = vt + ((size_t)(b * 8 + kv) * 32 + tile) * 4096 + tl * 64 + q * 16;
    *reinterpret_cast<int4*>(dst) = reinterpret_cast<int4*>(buf)[0];
    *reinterpret_cast<int4*>(dst + 8) = reinterpret_cast<int4*>(buf)[1];
}

// ---------------------------------------------------------------------------
// Flash attention, causal GQA, swapped-QK^T form, double-buffered K/V,
// load-balanced: block p handles q-tiles (15-p) then p  => 34 iters/block.
// grid (8 pairs, 32 h, 2 b); 256 thr = 4 waves, 32 q rows per wave per tile.
// Q bf16 (B,H,T,64) pre-scaled by QMULT; K bf16 (B,KV,T,64);
// Vt tiles (B,KV,32,64d,64kv); out bf16 (B,T,H*64)
// ---------------------------------------------------------------------------
__global__ __launch_bounds__(256) void attn_fwd(const short* __restrict__ Qb,
                                                const short* __restrict__ Kb,
                                                const short* __restrict__ Vt,
                                                short* __restrict__ Ob) {
    __shared__ __align__(16) short sK[2][64 * 64];
    __shared__ __align__(16) short sV[2][64 * 64];
    __shared__ __align__(16) short sP[4][32 * 72];

    const int pair = blockIdx.x;  // 0..7
    const int h = blockIdx.y, b = blockIdx.z;
    const int kvh = h >> 2;
    const int tid = threadIdx.x, wave = tid >> 6, lane = tid & 63;
    const int lhi = lane >> 4, llo = lane & 15;

    const short* Qp = Qb + (size_t)(b * Hc + h) * Tc * 64;
    const short* Kp = Kb + (size_t)(b * KVc + kvh) * Tc * 64;
    const short* Vp = Vt + (size_t)(b * KVc + kvh) * 32 * 4096;

    // per-thread staging addresses (4 GLOAD16 per tile)
    const int srow0 = tid >> 3, sslot0 = tid & 7;
    const int srow1 = (256 + tid) >> 3, sslot1 = tid & 7;
    const int soff0 = (sslot0 ^ (srow0 & 7)) * 8;
    const int soff1 = (sslot1 ^ (srow1 & 7)) * 8;

#pragma unroll 1
    for (int sub = 0; sub < 2; ++sub) {
        const int qt = sub ? pair : 15 - pair;
        const int Q0 = qt * 128 + wave * 32;
        const int ktmax_w = (Q0 + 31) >> 6;
        const int nkt = 2 * qt + 2;

        bf16x8 qf[2][2];
#pragma unroll
        for (int q16 = 0; q16 < 2; ++q16)
#pragma unroll
            for (int kk = 0; kk < 2; ++kk)
                qf[q16][kk] = *reinterpret_cast<const bf16x8*>(
                    Qp + (size_t)(Q0 + q16 * 16 + llo) * 64 + kk * 32 + lhi * 8);

        f32x4 o[2][4] = {};
        float mreg[2] = {-1e30f, -1e30f};
        float lreg[2] = {0.f, 0.f};

        // prologue: stage tile 0 into buf 0
        {
            GLOAD16(Kp + (size_t)srow0 * 64 + soff0, &sK[0][tid * 8]);
            GLOAD16(Vp + (size_t)srow0 * 64 + soff0, &sV[0][tid * 8]);
            GLOAD16(Kp + (size_t)srow1 * 64 + soff1, &sK[0][(256 + tid) * 8]);
            GLOAD16(Vp + (size_t)srow1 * 64 + soff1, &sV[0][(256 + tid) * 8]);
        }
        int c = 0;

#pragma unroll 1
        for (int kt = 0; kt < nkt; ++kt) {
            const bool has_next = (kt + 1) < nkt;
            if (has_next) {
                const size_t kbase = (size_t)(kt + 1) * 4096;
                GLOAD16(Kp + kbase + srow0 * 64 + soff0, &sK[c ^ 1][tid * 8]);
                GLOAD16(Vp + kbase + srow0 * 64 + soff0, &sV[c ^ 1][tid * 8]);
                GLOAD16(Kp + kbase + srow1 * 64 + soff1, &sK[c ^ 1][(256 + tid) * 8]);
                GLOAD16(Vp + kbase + srow1 * 64 + soff1, &sV[c ^ 1][(256 + tid) * 8]);
                asm volatile("s_waitcnt vmcnt(4)" ::: "memory");
            } else {
                asm volatile("s_waitcnt vmcnt(0)" ::: "memory");
            }
            __builtin_amdgcn_s_barrier();
            asm volatile("" ::: "memory");  // keep ds_reads below the barrier

            if (kt <= ktmax_w) {
                const short* sKc = sK[c];
                const short* sVc = sV[c];
                // S^T = K Q^T : C[kv_local=lhi*4+r][q_local=llo] per (n, q16)
                f32x4 st[2][4];
#pragma unroll
                for (int n = 0; n < 4; ++n) {
                    int krow = n * 16 + llo;
                    bf16x8 ka0 = *reinterpret_cast<const bf16x8*>(
                        &sKc[krow * 64 + ((lhi ^ (krow & 7)) << 3)]);
                    bf16x8 ka1 = *reinterpret_cast<const bf16x8*>(
                        &sKc[krow * 64 + (((4 + lhi) ^ (krow & 7)) << 3)]);
                    f32x4 z = {0.f, 0.f, 0.f, 0.f};
                    st[0][n] = __builtin_amdgcn_mfma_f32_16x16x32_bf16(ka0, qf[0][0], z, 0, 0, 0);
                    st[0][n] = __builtin_amdgcn_mfma_f32_16x16x32_bf16(ka1, qf[0][1], st[0][n], 0, 0, 0);
                    st[1][n] = __builtin_amdgcn_mfma_f32_16x16x32_bf16(ka0, qf[1][0], z, 0, 0, 0);
                    st[1][n] = __builtin_amdgcn_mfma_f32_16x16x32_bf16(ka1, qf[1][1], st[1][n], 0, 0, 0);
                }
                if (kt == ktmax_w) {  // causal mask (diagonal region only)
#pragma unroll
                    for (int q16 = 0; q16 < 2; ++q16) {
                        int qg = Q0 + q16 * 16 + llo;
#pragma unroll
                        for (int n = 0; n < 4; ++n)
#pragma unroll
                            for (int r = 0; r < 4; ++r) {
                                int kvg = kt * 64 + n * 16 + lhi * 4 + r;
                                if (kvg > qg) st[q16][n][r] = -1e30f;
                            }
                    }
                }
                // online softmax; lanes with same llo hold the same row stats
                float alpha[2];
#pragma unroll
                for (int q16 = 0; q16 < 2; ++q16) {
                    float pm = st[q16][0][0];
#pragma unroll
                    for (int n = 0; n < 4; ++n)
#pragma unroll
                        for (int r = 0; r < 4; ++r) pm = fmaxf(pm, st[q16][n][r]);
                    pm = fmaxf(pm, __shfl_xor(pm, 16));
                    pm = fmaxf(pm, __shfl_xor(pm, 32));
                    float mn = fmaxf(mreg[q16], pm);
                    alpha[q16] = __builtin_amdgcn_exp2f(mreg[q16] - mn);
                    mreg[q16] = mn;
                    float ps = 0.f;
#pragma unroll
                    for (int n = 0; n < 4; ++n)
#pragma unroll
                        for (int r = 0; r < 4; ++r) {
                            float p = __builtin_amdgcn_exp2f(st[q16][n][r] - mn);
                            st[q16][n][r] = p;
                            ps += p;
                        }
                    ps += __shfl_xor(ps, 16);
                    ps += __shfl_xor(ps, 32);
                    lreg[q16] = lreg[q16] * alpha[q16] + ps;
                }
                // rescale O (alpha lives at lane llo==row; broadcast to C rows)
#pragma unroll
                for (int q16 = 0; q16 < 2; ++q16)
#pragma unroll
                    for (int r = 0; r < 4; ++r) {
                        float ar = __shfl(alpha[q16], lhi * 4 + r);
#pragma unroll
                        for (int j = 0; j < 4; ++j) o[q16][j][r] *= ar;
                    }
                // store P rows to wave-private LDS (b64 stores)
#pragma unroll
                for (int q16 = 0; q16 < 2; ++q16)
#pragma unroll
                    for (int n = 0; n < 4; ++n) {
                        short4v p4 = {f2b(st[q16][n][0]), f2b(st[q16][n][1]),
                                      f2b(st[q16][n][2]), f2b(st[q16][n][3])};
                        *reinterpret_cast<short4v*>(
                            &sP[wave][(q16 * 16 + llo) * 72 + n * 16 + lhi * 4]) = p4;
                    }
                // O += P V
#pragma unroll
                for (int kk = 0; kk < 2; ++kk) {
                    bf16x8 pa0 = *reinterpret_cast<const bf16x8*>(
                        &sP[wave][(0 * 16 + llo) * 72 + kk * 32 + lhi * 8]);
                    bf16x8 pa1 = *reinterpret_cast<const bf16x8*>(
                        &sP[wave][(1 * 16 + llo) * 72 + kk * 32 + lhi * 8]);
#pragma unroll
                    for (int j = 0; j < 4; ++j) {
                        int vrow = j * 16 + llo;
                        bf16x8 vf = *reinterpret_cast<const bf16x8*>(
                            &sVc[vrow * 64 + ((((kk * 4) + lhi) ^ (vrow & 7)) << 3)]);
                        o[0][j] = __builtin_amdgcn_mfma_f32_16x16x32_bf16(pa0, vf, o[0][j], 0, 0, 0);
                        o[1][j] = __builtin_amdgcn_mfma_f32_16x16x32_bf16(pa1, vf, o[1][j], 0, 0, 0);
                    }
                }
            }
            asm volatile("" ::: "memory");  // keep ds_reads above the barrier
            __builtin_amdgcn_s_barrier();
            c ^= 1;
        }

        // epilogue: normalize, store bf16 (B,T,H*64)
#pragma unroll
        for (int q16 = 0; q16 < 2; ++q16) {
            float inv = 1.0f / lreg[q16];
#pragma unroll
            for (int r = 0; r < 4; ++r) {
                float ivr = __shfl(inv, lhi * 4 + r);
                int qrow = Q0 + q16 * 16 + lhi * 4 + r;
#pragma unroll
                for (int j = 0; j < 4; ++j)
                    Ob[((size_t)(b * Tc + qrow)) * 2048 + h * 64 + j * 16 + llo] =
                        f2b(o[q16][j][r] * ivr);
            }
        }
    }
}

// ---------------------------------------------------------------------------
extern "C" void kernel_launch(void* const* d_in, const int* in_sizes, int n_in,
                              void* d_out, int out_size, void* d_ws, size_t ws_size,
                              hipStream_t stream) {
    const float* x  = (const float*)d_in[0];
    const float* Wq = (const float*)d_in[1];
    const float* Wk = (const float*)d_in[2];
    const float* Wv = (const float*)d_in[3];
    const float* Wo = (const float*)d_in[4];
    const float* qs = (const float*)d_in[5];
    const float* ks = (const float*)d_in[6];
    float* out = (float*)d_out;

    char* w = (char*)d_ws;
    short* xb   = (short*)(w);                  // 16,777,216  (later: ob)
    short* WqT  = (short*)(w + 16777216);       //  8,388,608  (later: vt)
    short* WkvT = (short*)(w + 25165824);       //  4,194,304
    short* WoT  = (short*)(w + 29360128);       //  8,388,608
    short* qfb  = (short*)(w + 37748736);       // 16,777,216
    short* kvf  = (short*)(w + 54525952);       //  8,388,608
    short* qb   = (short*)(w + 62914560);       // 16,777,216
    short* kb   = (short*)(w + 79691776);       //  4,194,304
    short* vt   = WqT;                          // alias (WqT dead after Q gemm)
    short* ob   = xb;                           // alias (xb dead after gemms)

    dim3 blk(256);
    // prep: bf16 convert + weight transposes
    convert_x<<<dim3(4096), blk, 0, stream>>>(x, xb);
    tr_w<<<dim3(32, 32), blk, 0, stream>>>(Wq, WqT, 2048, 2048);
    tr_w<<<dim3(8, 32), blk, 0, stream>>>(Wk, WkvT, 2048, 512);
    tr_w<<<dim3(8, 32), blk, 0, stream>>>(Wv, WkvT + (size_t)512 * 2048, 2048, 512);
    tr_w<<<dim3(32, 32), blk, 0, stream>>>(Wo, WoT, 2048, 2048);
    // projections (bf16 out)
    gemm_bt<short><<<dim3(16, 32), blk, 0, stream>>>(xb, WqT, qfb, 4096, 2048, 2048);
    gemm_bt<short><<<dim3(8, 32), blk, 0, stream>>>(xb, WkvT, kvf, 4096, 1024, 2048);
    // RMSNorm + RoPE (+SCALE*log2e on Q) + relayout
    fuse_qk<<<dim3(32768), blk, 0, stream>>>(qfb, qs, qb, Hc, 2048, QMULT);
    fuse_qk<<<dim3(8192), blk, 0, stream>>>(kvf, ks, kb, KVc, 1024, 1.0f);
    fuse_vt<<<dim3(32, 8, 2), blk, 0, stream>>>(kvf, vt);
    // flash attention
    attn_fwd<<<dim3(8, 32, 2), blk, 0, stream>>>(qb, kb, vt, ob);
    // output projection (f32 out)
    gemm_bt<float><<<dim3(16, 32), blk, 0, stream>>>(ob, WoT, out, 4096, 2048, 2048);
}

// Round 5
// 271.362 us; speedup vs baseline: 2.4998x; 1.1499x over previous
//
#include <hip/hip_runtime.h>
#include <hip/hip_bf16.h>

typedef __attribute__((ext_vector_type(4))) float f32x4;
typedef __attribute__((ext_vector_type(8))) short bf16x8;
typedef __attribute__((ext_vector_type(4))) short short4v;

#define DEVI __device__ __forceinline__

constexpr int Bc = 2, Tc = 2048, Dc = 2048, Hc = 32, KVc = 8, HDc = 64;
constexpr int GRP = Hc / KVc;  // 4
constexpr float EPSc = 1e-6f;
// SCALE * log2(e) folded into Q so softmax uses exp2
constexpr float QMULT = 0.125f * 1.4426950408889634f;

DEVI short f2b(float f) {
    __hip_bfloat16 h = __float2bfloat16(f);
    short s;
    __builtin_memcpy(&s, &h, sizeof(short));
    return s;
}
DEVI float b2f(short s) {
    unsigned int u = ((unsigned int)(unsigned short)s) << 16;
    float f;
    __builtin_memcpy(&f, &u, sizeof(float));
    return f;
}

#define GLOAD16(g, l)                                                        \
    __builtin_amdgcn_global_load_lds(                                        \
        (const __attribute__((address_space(1))) void*)(g),                  \
        (__attribute__((address_space(3))) void*)(l), 16, 0, 0)

// ---------------------------------------------------------------------------
// prep: f32 -> bf16 convert (x), each thread 8 elems
// ---------------------------------------------------------------------------
__global__ __launch_bounds__(256) void convert_x(const float* __restrict__ in,
                                                 short* __restrict__ out) {
    size_t i = ((size_t)blockIdx.x * 256 + threadIdx.x) * 8;
    float4 a = *reinterpret_cast<const float4*>(in + i);
    float4 b = *reinterpret_cast<const float4*>(in + i + 4);
    bf16x8 o = {f2b(a.x), f2b(a.y), f2b(a.z), f2b(a.w),
                f2b(b.x), f2b(b.y), f2b(b.z), f2b(b.w)};
    *reinterpret_cast<bf16x8*>(out + i) = o;
}

// ---------------------------------------------------------------------------
// prep: transpose weight f32 (R x C) -> bf16 (C x R).  grid (C/64, R/64)
// ---------------------------------------------------------------------------
__global__ __launch_bounds__(256) void tr_w(const float* __restrict__ in,
                                            short* __restrict__ out, int R, int C) {
    __shared__ __align__(16) short t[64][72];
    const int n0 = blockIdx.x * 64, k0 = blockIdx.y * 64;
    const int rl = threadIdx.x >> 2, q = threadIdx.x & 3;
#pragma unroll
    for (int jj = 0; jj < 4; ++jj) {
        float4 v = *reinterpret_cast<const float4*>(in + (size_t)(k0 + rl) * C + n0 + q * 16 + jj * 4);
        short4v s = {f2b(v.x), f2b(v.y), f2b(v.z), f2b(v.w)};
        *reinterpret_cast<short4v*>(&t[rl][q * 16 + jj * 4]) = s;
    }
    __syncthreads();
    alignas(16) short buf[16];
#pragma unroll
    for (int e = 0; e < 16; ++e) buf[e] = t[q * 16 + e][rl];
    short* dst = out + (size_t)(n0 + rl) * R + k0 + q * 16;
    *reinterpret_cast<int4*>(dst) = reinterpret_cast<int4*>(buf)[0];
    *reinterpret_cast<int4*>(dst + 8) = reinterpret_cast<int4*>(buf)[1];
}

// ---------------------------------------------------------------------------
// GEMM: C(MxN) = A(MxK,bf16 rowmajor) * Bt(NxK,bf16 rowmajor)^T
// 128x128 tile, BK=32, 256 thr (4 waves 2x2), global_load_lds w16 staging,
// double-buffered LDS with counted vmcnt (loads stay in flight across barriers)
// ---------------------------------------------------------------------------
template <typename CT>
__global__ __launch_bounds__(256) void gemm_bt(const short* __restrict__ A,
                                               const short* __restrict__ Bt,
                                               CT* __restrict__ C, int M, int N, int K) {
    __shared__ __align__(16) short sA[2][128 * 32];
    __shared__ __align__(16) short sB[2][128 * 32];

    const int tid = threadIdx.x;
    const int wave = tid >> 6, lane = tid & 63;
    const int lhi = lane >> 4, llo = lane & 15;
    const int bm = blockIdx.y * 128, bn = blockIdx.x * 128;
    const int wm = (wave >> 1) * 64, wn = (wave & 1) * 64;

    // staging addresses: element c in [0,512): row c>>2, 8-elem chunk (c&3)*8
    const int r0 = tid >> 2, ch0 = (tid & 3) * 8;
    const int r1 = (256 + tid) >> 2;
    const short* Ab0 = A + (size_t)(bm + r0) * K + ch0;
    const short* Ab1 = A + (size_t)(bm + r1) * K + ch0;
    const short* Bb0 = Bt + (size_t)(bn + r0) * K + ch0;
    const short* Bb1 = Bt + (size_t)(bn + r1) * K + ch0;

    f32x4 acc[4][4] = {};

    // prologue: stage K-tile 0 into buf 0
    GLOAD16(Ab0, &sA[0][tid * 8]);
    GLOAD16(Bb0, &sB[0][tid * 8]);
    GLOAD16(Ab1, &sA[0][(256 + tid) * 8]);
    GLOAD16(Bb1, &sB[0][(256 + tid) * 8]);
    int c = 0;

#pragma unroll 1
    for (int k0 = 0; k0 < K; k0 += 32) {
        if (k0 + 32 < K) {
            const int kn = k0 + 32;
            GLOAD16(Ab0 + kn, &sA[c ^ 1][tid * 8]);
            GLOAD16(Bb0 + kn, &sB[c ^ 1][tid * 8]);
            GLOAD16(Ab1 + kn, &sA[c ^ 1][(256 + tid) * 8]);
            GLOAD16(Bb1 + kn, &sB[c ^ 1][(256 + tid) * 8]);
            asm volatile("s_waitcnt vmcnt(4)" ::: "memory");
        } else {
            asm volatile("s_waitcnt vmcnt(0)" ::: "memory");
        }
        __builtin_amdgcn_s_barrier();
        asm volatile("" ::: "memory");  // keep ds_reads below the barrier

        bf16x8 af[4], bf[4];
#pragma unroll
        for (int i = 0; i < 4; ++i)
            af[i] = *reinterpret_cast<const bf16x8*>(&sA[c][(wm + i * 16 + llo) * 32 + lhi * 8]);
#pragma unroll
        for (int j = 0; j < 4; ++j)
            bf[j] = *reinterpret_cast<const bf16x8*>(&sB[c][(wn + j * 16 + llo) * 32 + lhi * 8]);
#pragma unroll
        for (int i = 0; i < 4; ++i)
#pragma unroll
            for (int j = 0; j < 4; ++j)
                acc[i][j] = __builtin_amdgcn_mfma_f32_16x16x32_bf16(af[i], bf[j], acc[i][j], 0, 0, 0);

        asm volatile("" ::: "memory");  // keep ds_reads above the barrier
        __builtin_amdgcn_s_barrier();
        c ^= 1;
    }

#pragma unroll
    for (int i = 0; i < 4; ++i)
#pragma unroll
        for (int j = 0; j < 4; ++j)
#pragma unroll
            for (int r = 0; r < 4; ++r) {
                size_t idx = (size_t)(bm + wm + i * 16 + lhi * 4 + r) * N + bn + wn + j * 16 + llo;
                if constexpr (sizeof(CT) == 2)
                    C[idx] = f2b(acc[i][j][r]);
                else
                    C[idx] = acc[i][j][r];
            }
}

// ---------------------------------------------------------------------------
// fuse: RMSNorm + RoPE + scale, bf16 (B*T rows, stride ldin) -> bf16 (B,Hx,T,64)
// one 64-lane wave per row
// ---------------------------------------------------------------------------
__global__ __launch_bounds__(256) void fuse_qk(const short* __restrict__ in,
                                               const float* __restrict__ scale,
                                               short* __restrict__ out, int Hx, int ldin,
                                               float mult) {
    int wid = (blockIdx.x * 256 + threadIdx.x) >> 6;
    int d = threadIdx.x & 63;
    if (wid >= Bc * Tc * Hx) return;
    int h = wid % Hx;
    int bt = wid / Hx;
    int t = bt % Tc;
    int b = bt / Tc;

    float v = b2f(in[(size_t)bt * ldin + h * 64 + d]);
    float ss = v * v;
#pragma unroll
    for (int m = 1; m < 64; m <<= 1) ss += __shfl_xor(ss, m);
    v = v / sqrtf(ss * (1.0f / 64.0f) + EPSc) * scale[d];

    int i = d & 31;
    float inv_f = exp2f(-0.41524101186092029f * (float)i);  // theta^(-i/32)
    float ang = (float)t * inv_f;
    float sn, cs;
    sincosf(ang, &sn, &cs);
    float other = __shfl_xor(v, 32);
    float o = (d < 32) ? (v * cs - other * sn) : (v * cs + other * sn);
    o *= mult;
    out[((size_t)(b * Hx + h) * Tc + t) * 64 + d] = f2b(o);
}

// ---------------------------------------------------------------------------
// fuse: V rows (stride ldin, base pre-offset to V cols) -> transposed tiles
// vt[b][kv][tile][d(64)][t_local(64)].  grid (32 tiles, 8 kv, 2 b)
// ---------------------------------------------------------------------------
__global__ __launch_bounds__(256) void fuse_vt(const short* __restrict__ vsrc,
                                               short* __restrict__ vt, int ldin) {
    __shared__ __align__(16) short t[64][72];
    const int tile = blockIdx.x, kv = blockIdx.y, b = blockIdx.z;
    const int tl = threadIdx.x >> 2, q = threadIdx.x & 3;
    const short* src = vsrc + (size_t)(b * 2048 + tile * 64 + tl) * ldin + kv * 64 + q * 16;
    *reinterpret_cast<bf16x8*>(&t[tl][q * 16]) = *reinterpret_cast<const bf16x8*>(src);
    *reinterpret_cast<bf16x8*>(&t[tl][q * 16 + 8]) = *reinterpret_cast<const bf16x8*>(src + 8);
    __syncthreads();
    alignas(16) short buf[16];
#pragma unroll
    for (int e = 0; e < 16; ++e) buf[e] = t[q * 16 + e][tl];
    short* dst = vt + ((size_t)(b * 8 + kv) * 32 + tile) * 4096 + tl * 64 + q * 16;
    *reinterpret_cast<int4*>(dst) = reinterpret_cast<int4*>(buf)[0];
    *reinterpret_cast<int4*>(dst + 8) = reinterpret_cast<int4*>(buf)[1];
}

// ---------------------------------------------------------------------------
// Flash attention, causal GQA, swapped-QK^T form, double-buffered K/V,
// load-balanced: block p handles q-tiles (15-p) then p  => 34 iters/block.
// grid (8 pairs, 32 h, 2 b); 256 thr = 4 waves, 32 q rows per wave per tile.
// ---------------------------------------------------------------------------
__global__ __launch_bounds__(256) void attn_fwd(const short* __restrict__ Qb,
                                                const short* __restrict__ Kb,
                                                const short* __restrict__ Vt,
                                                short* __restrict__ Ob) {
    __shared__ __align__(16) short sK[2][64 * 64];
    __shared__ __align__(16) short sV[2][64 * 64];
    __shared__ __align__(16) short sP[4][32 * 72];

    const int pair = blockIdx.x;  // 0..7
    const int h = blockIdx.y, b = blockIdx.z;
    const int kvh = h >> 2;
    const int tid = threadIdx.x, wave = tid >> 6, lane = tid & 63;
    const int lhi = lane >> 4, llo = lane & 15;

    const short* Qp = Qb + (size_t)(b * Hc + h) * Tc * 64;
    const short* Kp = Kb + (size_t)(b * KVc + kvh) * Tc * 64;
    const short* Vp = Vt + (size_t)(b * KVc + kvh) * 32 * 4096;

    // per-thread staging addresses (4 GLOAD16 per tile)
    const int srow0 = tid >> 3, sslot0 = tid & 7;
    const int srow1 = (256 + tid) >> 3, sslot1 = tid & 7;
    const int soff0 = (sslot0 ^ (srow0 & 7)) * 8;
    const int soff1 = (sslot1 ^ (srow1 & 7)) * 8;

#pragma unroll 1
    for (int sub = 0; sub < 2; ++sub) {
        const int qt = sub ? pair : 15 - pair;
        const int Q0 = qt * 128 + wave * 32;
        const int ktmax_w = (Q0 + 31) >> 6;
        const int nkt = 2 * qt + 2;

        bf16x8 qf[2][2];
#pragma unroll
        for (int q16 = 0; q16 < 2; ++q16)
#pragma unroll
            for (int kk = 0; kk < 2; ++kk)
                qf[q16][kk] = *reinterpret_cast<const bf16x8*>(
                    Qp + (size_t)(Q0 + q16 * 16 + llo) * 64 + kk * 32 + lhi * 8);

        f32x4 o[2][4] = {};
        float mreg[2] = {-1e30f, -1e30f};
        float lreg[2] = {0.f, 0.f};

        // prologue: stage tile 0 into buf 0
        {
            GLOAD16(Kp + (size_t)srow0 * 64 + soff0, &sK[0][tid * 8]);
            GLOAD16(Vp + (size_t)srow0 * 64 + soff0, &sV[0][tid * 8]);
            GLOAD16(Kp + (size_t)srow1 * 64 + soff1, &sK[0][(256 + tid) * 8]);
            GLOAD16(Vp + (size_t)srow1 * 64 + soff1, &sV[0][(256 + tid) * 8]);
        }
        int c = 0;

#pragma unroll 1
        for (int kt = 0; kt < nkt; ++kt) {
            const bool has_next = (kt + 1) < nkt;
            if (has_next) {
                const size_t kbase = (size_t)(kt + 1) * 4096;
                GLOAD16(Kp + kbase + srow0 * 64 + soff0, &sK[c ^ 1][tid * 8]);
                GLOAD16(Vp + kbase + srow0 * 64 + soff0, &sV[c ^ 1][tid * 8]);
                GLOAD16(Kp + kbase + srow1 * 64 + soff1, &sK[c ^ 1][(256 + tid) * 8]);
                GLOAD16(Vp + kbase + srow1 * 64 + soff1, &sV[c ^ 1][(256 + tid) * 8]);
                asm volatile("s_waitcnt vmcnt(4)" ::: "memory");
            } else {
                asm volatile("s_waitcnt vmcnt(0)" ::: "memory");
            }
            __builtin_amdgcn_s_barrier();
            asm volatile("" ::: "memory");  // keep ds_reads below the barrier

            if (kt <= ktmax_w) {
                const short* sKc = sK[c];
                const short* sVc = sV[c];
                // S^T = K Q^T : C[kv_local=lhi*4+r][q_local=llo] per (n, q16)
                f32x4 st[2][4];
#pragma unroll
                for (int n = 0; n < 4; ++n) {
                    int krow = n * 16 + llo;
                    bf16x8 ka0 = *reinterpret_cast<const bf16x8*>(
                        &sKc[krow * 64 + ((lhi ^ (krow & 7)) << 3)]);
                    bf16x8 ka1 = *reinterpret_cast<const bf16x8*>(
                        &sKc[krow * 64 + (((4 + lhi) ^ (krow & 7)) << 3)]);
                    f32x4 z = {0.f, 0.f, 0.f, 0.f};
                    st[0][n] = __builtin_amdgcn_mfma_f32_16x16x32_bf16(ka0, qf[0][0], z, 0, 0, 0);
                    st[0][n] = __builtin_amdgcn_mfma_f32_16x16x32_bf16(ka1, qf[0][1], st[0][n], 0, 0, 0);
                    st[1][n] = __builtin_amdgcn_mfma_f32_16x16x32_bf16(ka0, qf[1][0], z, 0, 0, 0);
                    st[1][n] = __builtin_amdgcn_mfma_f32_16x16x32_bf16(ka1, qf[1][1], st[1][n], 0, 0, 0);
                }
                if (kt == ktmax_w) {  // causal mask (diagonal region only)
#pragma unroll
                    for (int q16 = 0; q16 < 2; ++q16) {
                        int qg = Q0 + q16 * 16 + llo;
#pragma unroll
                        for (int n = 0; n < 4; ++n)
#pragma unroll
                            for (int r = 0; r < 4; ++r) {
                                int kvg = kt * 64 + n * 16 + lhi * 4 + r;
                                if (kvg > qg) st[q16][n][r] = -1e30f;
                            }
                    }
                }
                // online softmax; lanes with same llo hold the same row stats
                float alpha[2];
#pragma unroll
                for (int q16 = 0; q16 < 2; ++q16) {
                    float pm = st[q16][0][0];
#pragma unroll
                    for (int n = 0; n < 4; ++n)
#pragma unroll
                        for (int r = 0; r < 4; ++r) pm = fmaxf(pm, st[q16][n][r]);
                    pm = fmaxf(pm, __shfl_xor(pm, 16));
                    pm = fmaxf(pm, __shfl_xor(pm, 32));
                    float mn = fmaxf(mreg[q16], pm);
                    alpha[q16] = __builtin_amdgcn_exp2f(mreg[q16] - mn);
                    mreg[q16] = mn;
                    float ps = 0.f;
#pragma unroll
                    for (int n = 0; n < 4; ++n)
#pragma unroll
                        for (int r = 0; r < 4; ++r) {
                            float p = __builtin_amdgcn_exp2f(st[q16][n][r] - mn);
                            st[q16][n][r] = p;
                            ps += p;
                        }
                    ps += __shfl_xor(ps, 16);
                    ps += __shfl_xor(ps, 32);
                    lreg[q16] = lreg[q16] * alpha[q16] + ps;
                }
                // rescale O (alpha lives at lane llo==row; broadcast to C rows)
#pragma unroll
                for (int q16 = 0; q16 < 2; ++q16)
#pragma unroll
                    for (int r = 0; r < 4; ++r) {
                        float ar = __shfl(alpha[q16], lhi * 4 + r);
#pragma unroll
                        for (int j = 0; j < 4; ++j) o[q16][j][r] *= ar;
                    }
                // store P rows to wave-private LDS (b64 stores)
#pragma unroll
                for (int q16 = 0; q16 < 2; ++q16)
#pragma unroll
                    for (int n = 0; n < 4; ++n) {
                        short4v p4 = {f2b(st[q16][n][0]), f2b(st[q16][n][1]),
                                      f2b(st[q16][n][2]), f2b(st[q16][n][3])};
                        *reinterpret_cast<short4v*>(
                            &sP[wave][(q16 * 16 + llo) * 72 + n * 16 + lhi * 4]) = p4;
                    }
                // O += P V
#pragma unroll
                for (int kk = 0; kk < 2; ++kk) {
                    bf16x8 pa0 = *reinterpret_cast<const bf16x8*>(
                        &sP[wave][(0 * 16 + llo) * 72 + kk * 32 + lhi * 8]);
                    bf16x8 pa1 = *reinterpret_cast<const bf16x8*>(
                        &sP[wave][(1 * 16 + llo) * 72 + kk * 32 + lhi * 8]);
#pragma unroll
                    for (int j = 0; j < 4; ++j) {
                        int vrow = j * 16 + llo;
                        bf16x8 vf = *reinterpret_cast<const bf16x8*>(
                            &sVc[vrow * 64 + ((((kk * 4) + lhi) ^ (vrow & 7)) << 3)]);
                        o[0][j] = __builtin_amdgcn_mfma_f32_16x16x32_bf16(pa0, vf, o[0][j], 0, 0, 0);
                        o[1][j] = __builtin_amdgcn_mfma_f32_16x16x32_bf16(pa1, vf, o[1][j], 0, 0, 0);
                    }
                }
            }
            asm volatile("" ::: "memory");  // keep ds_reads above the barrier
            __builtin_amdgcn_s_barrier();
            c ^= 1;
        }

        // epilogue: normalize, store bf16 (B,T,H*64)
#pragma unroll
        for (int q16 = 0; q16 < 2; ++q16) {
            float inv = 1.0f / lreg[q16];
#pragma unroll
            for (int r = 0; r < 4; ++r) {
                float ivr = __shfl(inv, lhi * 4 + r);
                int qrow = Q0 + q16 * 16 + lhi * 4 + r;
#pragma unroll
                for (int j = 0; j < 4; ++j)
                    Ob[((size_t)(b * Tc + qrow)) * 2048 + h * 64 + j * 16 + llo] =
                        f2b(o[q16][j][r] * ivr);
            }
        }
    }
}

// ---------------------------------------------------------------------------
extern "C" void kernel_launch(void* const* d_in, const int* in_sizes, int n_in,
                              void* d_out, int out_size, void* d_ws, size_t ws_size,
                              hipStream_t stream) {
    const float* x  = (const float*)d_in[0];
    const float* Wq = (const float*)d_in[1];
    const float* Wk = (const float*)d_in[2];
    const float* Wv = (const float*)d_in[3];
    const float* Wo = (const float*)d_in[4];
    const float* qs = (const float*)d_in[5];
    const float* ks = (const float*)d_in[6];
    float* out = (float*)d_out;

    char* w = (char*)d_ws;
    short* xb   = (short*)(w);                  // 16,777,216  (later: ob)
    short* WqkvT = (short*)(w + 16777216);      // 12,582,912  (3072 x 2048) (later: vt)
    short* WoT  = (short*)(w + 29360128);       //  8,388,608
    short* qkvf = (short*)(w + 37748736);       // 25,165,824  (4096 x 3072)
    short* qb   = (short*)(w + 62914560);       // 16,777,216
    short* kb   = (short*)(w + 79691776);       //  4,194,304
    short* vt   = WqkvT;                        // alias (WqkvT dead after proj gemm)
    short* ob   = xb;                           // alias (xb dead after proj gemm)

    dim3 blk(256);
    // prep: bf16 convert + weight transposes (B^T rows: 0-2047 Wq, 2048-2559 Wk, 2560-3071 Wv)
    convert_x<<<dim3(4096), blk, 0, stream>>>(x, xb);
    tr_w<<<dim3(32, 32), blk, 0, stream>>>(Wq, WqkvT, 2048, 2048);
    tr_w<<<dim3(8, 32), blk, 0, stream>>>(Wk, WqkvT + (size_t)2048 * 2048, 2048, 512);
    tr_w<<<dim3(8, 32), blk, 0, stream>>>(Wv, WqkvT + (size_t)2560 * 2048, 2048, 512);
    tr_w<<<dim3(32, 32), blk, 0, stream>>>(Wo, WoT, 2048, 2048);
    // fused QKV projection (bf16 out, 4096 x 3072, cols 0-2047 q / 2048-2559 k / 2560-3071 v)
    gemm_bt<short><<<dim3(24, 32), blk, 0, stream>>>(xb, WqkvT, qkvf, 4096, 3072, 2048);
    // RMSNorm + RoPE (+SCALE*log2e on Q) + relayout
    fuse_qk<<<dim3(32768), blk, 0, stream>>>(qkvf, qs, qb, Hc, 3072, QMULT);
    fuse_qk<<<dim3(8192), blk, 0, stream>>>(qkvf + 2048, ks, kb, KVc, 3072, 1.0f);
    fuse_vt<<<dim3(32, 8, 2), blk, 0, stream>>>(qkvf + 2560, vt, 3072);
    // flash attention
    attn_fwd<<<dim3(8, 32, 2), blk, 0, stream>>>(qb, kb, vt, ob);
    // output projection (f32 out)
    gemm_bt<float><<<dim3(16, 32), blk, 0, stream>>>(ob, WoT, out, 4096, 2048, 2048);
}

// Round 6
// 260.608 us; speedup vs baseline: 2.6030x; 1.0413x over previous
//
#include <hip/hip_runtime.h>
#include <hip/hip_bf16.h>

typedef __attribute__((ext_vector_type(4))) float f32x4;
typedef __attribute__((ext_vector_type(8))) short bf16x8;
typedef __attribute__((ext_vector_type(4))) short short4v;

#define DEVI __device__ __forceinline__

constexpr int Bc = 2, Tc = 2048, Dc = 2048, Hc = 32, KVc = 8, HDc = 64;
constexpr int GRP = Hc / KVc;  // 4
constexpr float EPSc = 1e-6f;
// SCALE * log2(e) folded into Q so softmax uses exp2
constexpr float QMULT = 0.125f * 1.4426950408889634f;

DEVI short f2b(float f) {
    __hip_bfloat16 h = __float2bfloat16(f);
    short s;
    __builtin_memcpy(&s, &h, sizeof(short));
    return s;
}
DEVI float b2f(short s) {
    unsigned int u = ((unsigned int)(unsigned short)s) << 16;
    float f;
    __builtin_memcpy(&f, &u, sizeof(float));
    return f;
}

#define GLOAD16(g, l)                                                        \
    __builtin_amdgcn_global_load_lds(                                        \
        (const __attribute__((address_space(1))) void*)(g),                  \
        (__attribute__((address_space(3))) void*)(l), 16, 0, 0)

// ---------------------------------------------------------------------------
// prep: f32 -> bf16 convert (x), each thread 8 elems
// ---------------------------------------------------------------------------
__global__ __launch_bounds__(256) void convert_x(const float* __restrict__ in,
                                                 short* __restrict__ out) {
    size_t i = ((size_t)blockIdx.x * 256 + threadIdx.x) * 8;
    float4 a = *reinterpret_cast<const float4*>(in + i);
    float4 b = *reinterpret_cast<const float4*>(in + i + 4);
    bf16x8 o = {f2b(a.x), f2b(a.y), f2b(a.z), f2b(a.w),
                f2b(b.x), f2b(b.y), f2b(b.z), f2b(b.w)};
    *reinterpret_cast<bf16x8*>(out + i) = o;
}

// ---------------------------------------------------------------------------
// prep: transpose weight f32 (R x C) -> bf16 (C x R).  grid (C/64, R/64)
// ---------------------------------------------------------------------------
__global__ __launch_bounds__(256) void tr_w(const float* __restrict__ in,
                                            short* __restrict__ out, int R, int C) {
    __shared__ __align__(16) short t[64][72];
    const int n0 = blockIdx.x * 64, k0 = blockIdx.y * 64;
    const int rl = threadIdx.x >> 2, q = threadIdx.x & 3;
#pragma unroll
    for (int jj = 0; jj < 4; ++jj) {
        float4 v = *reinterpret_cast<const float4*>(in + (size_t)(k0 + rl) * C + n0 + q * 16 + jj * 4);
        short4v s = {f2b(v.x), f2b(v.y), f2b(v.z), f2b(v.w)};
        *reinterpret_cast<short4v*>(&t[rl][q * 16 + jj * 4]) = s;
    }
    __syncthreads();
    alignas(16) short buf[16];
#pragma unroll
    for (int e = 0; e < 16; ++e) buf[e] = t[q * 16 + e][rl];
    short* dst = out + (size_t)(n0 + rl) * R + k0 + q * 16;
    *reinterpret_cast<int4*>(dst) = reinterpret_cast<int4*>(buf)[0];
    *reinterpret_cast<int4*>(dst + 8) = reinterpret_cast<int4*>(buf)[1];
}

// ---------------------------------------------------------------------------
// GEMM: C(MxN) = A(MxK,bf16 rowmajor) * Bt(NxK,bf16 rowmajor)^T
// 128x128 tile, BK=64, 256 thr (4 waves 2x2), global_load_lds w16 staging,
// double-buffered LDS + counted vmcnt; XOR chunk-swizzle (chunk ^= row&7) via
// pre-swizzled global source so ds_read_b128 is ~conflict-free (2-way).
// ---------------------------------------------------------------------------
template <typename CT>
__global__ __launch_bounds__(256) void gemm_bt(const short* __restrict__ A,
                                               const short* __restrict__ Bt,
                                               CT* __restrict__ C, int M, int N, int K) {
    __shared__ __align__(16) short sA[2][128 * 64];   // 16 KB each buf
    __shared__ __align__(16) short sB[2][128 * 64];

    const int tid = threadIdx.x;
    const int wave = tid >> 6, lane = tid & 63;
    const int lhi = lane >> 4, llo = lane & 15;
    const int bm = blockIdx.y * 128, bn = blockIdx.x * 128;
    const int wm = (wave >> 1) * 64, wn = (wave & 1) * 64;

    // staging: 4 load-rounds per array; chunk id c = l*256+tid in [0,1024)
    // row = c>>3, in-row chunk = c&7, source chunk pre-swizzled by ^(row&7)
    const short* apt[4];
    const short* bpt[4];
#pragma unroll
    for (int l = 0; l < 4; ++l) {
        int c = l * 256 + tid;
        int r = c >> 3, ck = (c & 7) ^ (r & 7);
        apt[l] = A + (size_t)(bm + r) * K + ck * 8;
        bpt[l] = Bt + (size_t)(bn + r) * K + ck * 8;
    }

    f32x4 acc[4][4] = {};

    // prologue: stage K-tile 0 into buf 0
#pragma unroll
    for (int l = 0; l < 4; ++l) {
        GLOAD16(apt[l], &sA[0][(l * 256 + tid) * 8]);
        GLOAD16(bpt[l], &sB[0][(l * 256 + tid) * 8]);
    }
    int c = 0;

    // read-side swizzled chunk offsets (lane-constant): row&7 == llo&7
    const int co0 = ((lhi ^ (llo & 7)) << 3);        // kk=0 chunks 0..3
    const int co1 = (((4 + lhi) ^ (llo & 7)) << 3);  // kk=1 chunks 4..7

#pragma unroll 1
    for (int k0 = 0; k0 < K; k0 += 64) {
        if (k0 + 64 < K) {
            const int kn = k0 + 64;
#pragma unroll
            for (int l = 0; l < 4; ++l) {
                GLOAD16(apt[l] + kn, &sA[c ^ 1][(l * 256 + tid) * 8]);
                GLOAD16(bpt[l] + kn, &sB[c ^ 1][(l * 256 + tid) * 8]);
            }
            asm volatile("s_waitcnt vmcnt(8)" ::: "memory");
        } else {
            asm volatile("s_waitcnt vmcnt(0)" ::: "memory");
        }
        __builtin_amdgcn_s_barrier();
        asm volatile("" ::: "memory");  // keep ds_reads below the barrier

#pragma unroll
        for (int kk = 0; kk < 2; ++kk) {
            const int co = kk ? co1 : co0;
            bf16x8 af[4], bf[4];
#pragma unroll
            for (int i = 0; i < 4; ++i)
                af[i] = *reinterpret_cast<const bf16x8*>(&sA[c][(wm + i * 16 + llo) * 64 + co]);
#pragma unroll
            for (int j = 0; j < 4; ++j)
                bf[j] = *reinterpret_cast<const bf16x8*>(&sB[c][(wn + j * 16 + llo) * 64 + co]);
#pragma unroll
            for (int i = 0; i < 4; ++i)
#pragma unroll
                for (int j = 0; j < 4; ++j)
                    acc[i][j] = __builtin_amdgcn_mfma_f32_16x16x32_bf16(af[i], bf[j], acc[i][j], 0, 0, 0);
        }

        asm volatile("" ::: "memory");  // keep ds_reads above the barrier
        __builtin_amdgcn_s_barrier();
        c ^= 1;
    }

#pragma unroll
    for (int i = 0; i < 4; ++i)
#pragma unroll
        for (int j = 0; j < 4; ++j)
#pragma unroll
            for (int r = 0; r < 4; ++r) {
                size_t idx = (size_t)(bm + wm + i * 16 + lhi * 4 + r) * N + bn + wn + j * 16 + llo;
                if constexpr (sizeof(CT) == 2)
                    C[idx] = f2b(acc[i][j][r]);
                else
                    C[idx] = acc[i][j][r];
            }
}

// ---------------------------------------------------------------------------
// fuse: RMSNorm + RoPE + scale, bf16 (B*T rows, stride ldin) -> bf16 (B,Hx,T,64)
// one 64-lane wave per row
// ---------------------------------------------------------------------------
__global__ __launch_bounds__(256) void fuse_qk(const short* __restrict__ in,
                                               const float* __restrict__ scale,
                                               short* __restrict__ out, int Hx, int ldin,
                                               float mult) {
    int wid = (blockIdx.x * 256 + threadIdx.x) >> 6;
    int d = threadIdx.x & 63;
    if (wid >= Bc * Tc * Hx) return;
    int h = wid % Hx;
    int bt = wid / Hx;
    int t = bt % Tc;
    int b = bt / Tc;

    float v = b2f(in[(size_t)bt * ldin + h * 64 + d]);
    float ss = v * v;
#pragma unroll
    for (int m = 1; m < 64; m <<= 1) ss += __shfl_xor(ss, m);
    v = v / sqrtf(ss * (1.0f / 64.0f) + EPSc) * scale[d];

    int i = d & 31;
    float inv_f = exp2f(-0.41524101186092029f * (float)i);  // theta^(-i/32)
    float ang = (float)t * inv_f;
    float sn, cs;
    sincosf(ang, &sn, &cs);
    float other = __shfl_xor(v, 32);
    float o = (d < 32) ? (v * cs - other * sn) : (v * cs + other * sn);
    o *= mult;
    out[((size_t)(b * Hx + h) * Tc + t) * 64 + d] = f2b(o);
}

// ---------------------------------------------------------------------------
// fuse: V rows (stride ldin, base pre-offset to V cols) -> transposed tiles
// vt[b][kv][tile][d(64)][t_local(64)].  grid (32 tiles, 8 kv, 2 b)
// ---------------------------------------------------------------------------
__global__ __launch_bounds__(256) void fuse_vt(const short* __restrict__ vsrc,
                                               short* __restrict__ vt, int ldin) {
    __shared__ __align__(16) short t[64][72];
    const int tile = blockIdx.x, kv = blockIdx.y, b = blockIdx.z;
    const int tl = threadIdx.x >> 2, q = threadIdx.x & 3;
    const short* src = vsrc + (size_t)(b * 2048 + tile * 64 + tl) * ldin + kv * 64 + q * 16;
    *reinterpret_cast<bf16x8*>(&t[tl][q * 16]) = *reinterpret_cast<const bf16x8*>(src);
    *reinterpret_cast<bf16x8*>(&t[tl][q * 16 + 8]) = *reinterpret_cast<const bf16x8*>(src + 8);
    __syncthreads();
    alignas(16) short buf[16];
#pragma unroll
    for (int e = 0; e < 16; ++e) buf[e] = t[q * 16 + e][tl];
    short* dst = vt + ((size_t)(b * 8 + kv) * 32 + tile) * 4096 + tl * 64 + q * 16;
    *reinterpret_cast<int4*>(dst) = reinterpret_cast<int4*>(buf)[0];
    *reinterpret_cast<int4*>(dst + 8) = reinterpret_cast<int4*>(buf)[1];
}

// ---------------------------------------------------------------------------
// Flash attention, causal GQA, swapped-QK^T form, double-buffered K/V,
// load-balanced: block p handles q-tiles (15-p) then p  => 34 iters/block.
// grid (8 pairs, 32 h, 2 b); 256 thr = 4 waves, 32 q rows per wave per tile.
// Online softmax with defer-max (T13): skip O-rescale while tile max stays
// within 8 (exp2 units) of the running max.
// ---------------------------------------------------------------------------
__global__ __launch_bounds__(256) void attn_fwd(const short* __restrict__ Qb,
                                                const short* __restrict__ Kb,
                                                const short* __restrict__ Vt,
                                                short* __restrict__ Ob) {
    __shared__ __align__(16) short sK[2][64 * 64];
    __shared__ __align__(16) short sV[2][64 * 64];
    __shared__ __align__(16) short sP[4][32 * 72];

    const int pair = blockIdx.x;  // 0..7
    const int h = blockIdx.y, b = blockIdx.z;
    const int kvh = h >> 2;
    const int tid = threadIdx.x, wave = tid >> 6, lane = tid & 63;
    const int lhi = lane >> 4, llo = lane & 15;

    const short* Qp = Qb + (size_t)(b * Hc + h) * Tc * 64;
    const short* Kp = Kb + (size_t)(b * KVc + kvh) * Tc * 64;
    const short* Vp = Vt + (size_t)(b * KVc + kvh) * 32 * 4096;

    // per-thread staging addresses (4 GLOAD16 per tile)
    const int srow0 = tid >> 3, sslot0 = tid & 7;
    const int srow1 = (256 + tid) >> 3, sslot1 = tid & 7;
    const int soff0 = (sslot0 ^ (srow0 & 7)) * 8;
    const int soff1 = (sslot1 ^ (srow1 & 7)) * 8;

#pragma unroll 1
    for (int sub = 0; sub < 2; ++sub) {
        const int qt = sub ? pair : 15 - pair;
        const int Q0 = qt * 128 + wave * 32;
        const int ktmax_w = (Q0 + 31) >> 6;
        const int nkt = 2 * qt + 2;

        bf16x8 qf[2][2];
#pragma unroll
        for (int q16 = 0; q16 < 2; ++q16)
#pragma unroll
            for (int kk = 0; kk < 2; ++kk)
                qf[q16][kk] = *reinterpret_cast<const bf16x8*>(
                    Qp + (size_t)(Q0 + q16 * 16 + llo) * 64 + kk * 32 + lhi * 8);

        f32x4 o[2][4] = {};
        float mreg[2] = {-1e30f, -1e30f};
        float lreg[2] = {0.f, 0.f};

        // prologue: stage tile 0 into buf 0
        {
            GLOAD16(Kp + (size_t)srow0 * 64 + soff0, &sK[0][tid * 8]);
            GLOAD16(Vp + (size_t)srow0 * 64 + soff0, &sV[0][tid * 8]);
            GLOAD16(Kp + (size_t)srow1 * 64 + soff1, &sK[0][(256 + tid) * 8]);
            GLOAD16(Vp + (size_t)srow1 * 64 + soff1, &sV[0][(256 + tid) * 8]);
        }
        int c = 0;

#pragma unroll 1
        for (int kt = 0; kt < nkt; ++kt) {
            const bool has_next = (kt + 1) < nkt;
            if (has_next) {
                const size_t kbase = (size_t)(kt + 1) * 4096;
                GLOAD16(Kp + kbase + srow0 * 64 + soff0, &sK[c ^ 1][tid * 8]);
                GLOAD16(Vp + kbase + srow0 * 64 + soff0, &sV[c ^ 1][tid * 8]);
                GLOAD16(Kp + kbase + srow1 * 64 + soff1, &sK[c ^ 1][(256 + tid) * 8]);
                GLOAD16(Vp + kbase + srow1 * 64 + soff1, &sV[c ^ 1][(256 + tid) * 8]);
                asm volatile("s_waitcnt vmcnt(4)" ::: "memory");
            } else {
                asm volatile("s_waitcnt vmcnt(0)" ::: "memory");
            }
            __builtin_amdgcn_s_barrier();
            asm volatile("" ::: "memory");  // keep ds_reads below the barrier

            if (kt <= ktmax_w) {
                const short* sKc = sK[c];
                const short* sVc = sV[c];
                // S^T = K Q^T : C[kv_local=lhi*4+r][q_local=llo] per (n, q16)
                f32x4 st[2][4];
#pragma unroll
                for (int n = 0; n < 4; ++n) {
                    int krow = n * 16 + llo;
                    bf16x8 ka0 = *reinterpret_cast<const bf16x8*>(
                        &sKc[krow * 64 + ((lhi ^ (krow & 7)) << 3)]);
                    bf16x8 ka1 = *reinterpret_cast<const bf16x8*>(
                        &sKc[krow * 64 + (((4 + lhi) ^ (krow & 7)) << 3)]);
                    f32x4 z = {0.f, 0.f, 0.f, 0.f};
                    st[0][n] = __builtin_amdgcn_mfma_f32_16x16x32_bf16(ka0, qf[0][0], z, 0, 0, 0);
                    st[0][n] = __builtin_amdgcn_mfma_f32_16x16x32_bf16(ka1, qf[0][1], st[0][n], 0, 0, 0);
                    st[1][n] = __builtin_amdgcn_mfma_f32_16x16x32_bf16(ka0, qf[1][0], z, 0, 0, 0);
                    st[1][n] = __builtin_amdgcn_mfma_f32_16x16x32_bf16(ka1, qf[1][1], st[1][n], 0, 0, 0);
                }
                if (kt == ktmax_w) {  // causal mask (diagonal region only)
#pragma unroll
                    for (int q16 = 0; q16 < 2; ++q16) {
                        int qg = Q0 + q16 * 16 + llo;
#pragma unroll
                        for (int n = 0; n < 4; ++n)
#pragma unroll
                            for (int r = 0; r < 4; ++r) {
                                int kvg = kt * 64 + n * 16 + lhi * 4 + r;
                                if (kvg > qg) st[q16][n][r] = -1e30f;
                            }
                    }
                }
                // per-row tile max (lanes sharing llo hold the same row)
                float pm[2];
#pragma unroll
                for (int q16 = 0; q16 < 2; ++q16) {
                    float p = st[q16][0][0];
#pragma unroll
                    for (int n = 0; n < 4; ++n)
#pragma unroll
                        for (int r = 0; r < 4; ++r) p = fmaxf(p, st[q16][n][r]);
                    p = fmaxf(p, __shfl_xor(p, 16));
                    p = fmaxf(p, __shfl_xor(p, 32));
                    pm[q16] = p;
                }
                // defer-max: only rescale when tile max grew past running max + 8
                bool defer = __all((pm[0] - mreg[0] <= 8.f) && (pm[1] - mreg[1] <= 8.f));
                if (!defer) {
                    float alpha[2];
#pragma unroll
                    for (int q16 = 0; q16 < 2; ++q16) {
                        float mn = fmaxf(mreg[q16], pm[q16]);
                        alpha[q16] = __builtin_amdgcn_exp2f(mreg[q16] - mn);
                        mreg[q16] = mn;
                        lreg[q16] *= alpha[q16];
                    }
#pragma unroll
                    for (int q16 = 0; q16 < 2; ++q16)
#pragma unroll
                        for (int r = 0; r < 4; ++r) {
                            float ar = __shfl(alpha[q16], lhi * 4 + r);
#pragma unroll
                            for (int j = 0; j < 4; ++j) o[q16][j][r] *= ar;
                        }
                }
                // P = exp2(S - m); row sums
#pragma unroll
                for (int q16 = 0; q16 < 2; ++q16) {
                    float ps = 0.f;
#pragma unroll
                    for (int n = 0; n < 4; ++n)
#pragma unroll
                        for (int r = 0; r < 4; ++r) {
                            float p = __builtin_amdgcn_exp2f(st[q16][n][r] - mreg[q16]);
                            st[q16][n][r] = p;
                            ps += p;
                        }
                    ps += __shfl_xor(ps, 16);
                    ps += __shfl_xor(ps, 32);
                    lreg[q16] += ps;
                }
                // store P rows to wave-private LDS (b64 stores)
#pragma unroll
                for (int q16 = 0; q16 < 2; ++q16)
#pragma unroll
                    for (int n = 0; n < 4; ++n) {
                        short4v p4 = {f2b(st[q16][n][0]), f2b(st[q16][n][1]),
                                      f2b(st[q16][n][2]), f2b(st[q16][n][3])};
                        *reinterpret_cast<short4v*>(
                            &sP[wave][(q16 * 16 + llo) * 72 + n * 16 + lhi * 4]) = p4;
                    }
                // O += P V
#pragma unroll
                for (int kk = 0; kk < 2; ++kk) {
                    bf16x8 pa0 = *reinterpret_cast<const bf16x8*>(
                        &sP[wave][(0 * 16 + llo) * 72 + kk * 32 + lhi * 8]);
                    bf16x8 pa1 = *reinterpret_cast<const bf16x8*>(
                        &sP[wave][(1 * 16 + llo) * 72 + kk * 32 + lhi * 8]);
#pragma unroll
                    for (int j = 0; j < 4; ++j) {
                        int vrow = j * 16 + llo;
                        bf16x8 vf = *reinterpret_cast<const bf16x8*>(
                            &sVc[vrow * 64 + ((((kk * 4) + lhi) ^ (vrow & 7)) << 3)]);
                        o[0][j] = __builtin_amdgcn_mfma_f32_16x16x32_bf16(pa0, vf, o[0][j], 0, 0, 0);
                        o[1][j] = __builtin_amdgcn_mfma_f32_16x16x32_bf16(pa1, vf, o[1][j], 0, 0, 0);
                    }
                }
            }
            asm volatile("" ::: "memory");  // keep ds_reads above the barrier
            __builtin_amdgcn_s_barrier();
            c ^= 1;
        }

        // epilogue: normalize, store bf16 (B,T,H*64)
#pragma unroll
        for (int q16 = 0; q16 < 2; ++q16) {
            float inv = 1.0f / lreg[q16];
#pragma unroll
            for (int r = 0; r < 4; ++r) {
                float ivr = __shfl(inv, lhi * 4 + r);
                int qrow = Q0 + q16 * 16 + lhi * 4 + r;
#pragma unroll
                for (int j = 0; j < 4; ++j)
                    Ob[((size_t)(b * Tc + qrow)) * 2048 + h * 64 + j * 16 + llo] =
                        f2b(o[q16][j][r] * ivr);
            }
        }
    }
}

// ---------------------------------------------------------------------------
extern "C" void kernel_launch(void* const* d_in, const int* in_sizes, int n_in,
                              void* d_out, int out_size, void* d_ws, size_t ws_size,
                              hipStream_t stream) {
    const float* x  = (const float*)d_in[0];
    const float* Wq = (const float*)d_in[1];
    const float* Wk = (const float*)d_in[2];
    const float* Wv = (const float*)d_in[3];
    const float* Wo = (const float*)d_in[4];
    const float* qs = (const float*)d_in[5];
    const float* ks = (const float*)d_in[6];
    float* out = (float*)d_out;

    char* w = (char*)d_ws;
    short* xb   = (short*)(w);                  // 16,777,216  (later: ob)
    short* WqkvT = (short*)(w + 16777216);      // 12,582,912  (3072 x 2048) (later: vt)
    short* WoT  = (short*)(w + 29360128);       //  8,388,608
    short* qkvf = (short*)(w + 37748736);       // 25,165,824  (4096 x 3072)
    short* qb   = (short*)(w + 62914560);       // 16,777,216
    short* kb   = (short*)(w + 79691776);       //  4,194,304
    short* vt   = WqkvT;                        // alias (WqkvT dead after proj gemm)
    short* ob   = xb;                           // alias (xb dead after proj gemm)

    dim3 blk(256);
    // prep: bf16 convert + weight transposes (B^T rows: 0-2047 Wq, 2048-2559 Wk, 2560-3071 Wv)
    convert_x<<<dim3(4096), blk, 0, stream>>>(x, xb);
    tr_w<<<dim3(32, 32), blk, 0, stream>>>(Wq, WqkvT, 2048, 2048);
    tr_w<<<dim3(8, 32), blk, 0, stream>>>(Wk, WqkvT + (size_t)2048 * 2048, 2048, 512);
    tr_w<<<dim3(8, 32), blk, 0, stream>>>(Wv, WqkvT + (size_t)2560 * 2048, 2048, 512);
    tr_w<<<dim3(32, 32), blk, 0, stream>>>(Wo, WoT, 2048, 2048);
    // fused QKV projection (bf16 out, 4096 x 3072, cols 0-2047 q / 2048-2559 k / 2560-3071 v)
    gemm_bt<short><<<dim3(24, 32), blk, 0, stream>>>(xb, WqkvT, qkvf, 4096, 3072, 2048);
    // RMSNorm + RoPE (+SCALE*log2e on Q) + relayout
    fuse_qk<<<dim3(32768), blk, 0, stream>>>(qkvf, qs, qb, Hc, 3072, QMULT);
    fuse_qk<<<dim3(8192), blk, 0, stream>>>(qkvf + 2048, ks, kb, KVc, 3072, 1.0f);
    fuse_vt<<<dim3(32, 8, 2), blk, 0, stream>>>(qkvf + 2560, vt, 3072);
    // flash attention
    attn_fwd<<<dim3(8, 32, 2), blk, 0, stream>>>(qb, kb, vt, ob);
    // output projection (f32 out)
    gemm_bt<float><<<dim3(16, 32), blk, 0, stream>>>(ob, WoT, out, 4096, 2048, 2048);
}